// Round 1
// baseline (1993.380 us; speedup 1.0000x reference)
//
#include <hip/hip_runtime.h>

// ---------------------------------------------------------------------------
// SequenceModel: embed -> 2x transformer layer -> 3 output projections
// All GEMMs: C[M,N] = alpha * A[M,K] @ B[N,K]^T (+bias[col]) (+resid) (relu)
// A,B are _Float16; accum f32 via v_mfma_f32_16x16x32_f16.
// ---------------------------------------------------------------------------

typedef _Float16 half8 __attribute__((ext_vector_type(8)));
typedef _Float16 half4 __attribute__((ext_vector_type(4)));
typedef float f32x4 __attribute__((ext_vector_type(4)));

// ------------------------- elementwise cast f32->f16 -----------------------
__global__ void cast_f32_f16_k(const float* __restrict__ in, _Float16* __restrict__ out, long n) {
    long i = (long)blockIdx.x * blockDim.x + threadIdx.x;
    long stride = (long)gridDim.x * blockDim.x;
    for (; i < n; i += stride) out[i] = (_Float16)in[i];
}

// -------------- transpose+cast: in (Z,R,C) f32 -> out (Z,C,R) f16 ----------
__global__ void tcast_k(const float* __restrict__ in, _Float16* __restrict__ out, int R, int C) {
    __shared__ float tile[32][33];
    long z = blockIdx.z;
    const float* src = in + z * (long)R * C;
    _Float16* dst = out + z * (long)R * C;
    int c0 = blockIdx.x * 32, r0 = blockIdx.y * 32;
    for (int i = threadIdx.y; i < 32; i += 8)
        tile[i][threadIdx.x] = src[(long)(r0 + i) * C + c0 + threadIdx.x];
    __syncthreads();
    for (int i = threadIdx.y; i < 32; i += 8)
        dst[(long)(c0 + i) * R + r0 + threadIdx.x] = (_Float16)tile[threadIdx.x][i];
}

// -------- V transpose: v (B,S,H*hd) f16 -> vT (B*H, hd, S) f16 -------------
__global__ void vtrans_k(const _Float16* __restrict__ v, _Float16* __restrict__ vT) {
    __shared__ _Float16 tile[32][33];
    int bh = blockIdx.z; int b = bh >> 3, h = bh & 7;
    int s0 = blockIdx.x * 32, d0 = blockIdx.y * 32;
    const _Float16* src = v + ((long)b * 1024) * 512 + h * 64;  // [s][d], ld=512
    _Float16* dst = vT + (long)bh * 64 * 1024;                  // [d][s], ld=1024
    for (int i = threadIdx.y; i < 32; i += 8)
        tile[i][threadIdx.x] = src[(long)(s0 + i) * 512 + d0 + threadIdx.x];
    __syncthreads();
    for (int i = threadIdx.y; i < 32; i += 8)
        dst[(long)(d0 + i) * 1024 + s0 + threadIdx.x] = tile[threadIdx.x][i];
}

// ------------------------------- embedding ---------------------------------
__global__ __launch_bounds__(128) void embed_k(
    const int* __restrict__ ccat, const float* __restrict__ ctime, const float* __restrict__ cf0,
    const int* __restrict__ tcat, const float* __restrict__ ttime, const float* __restrict__ tf0,
    const float* __restrict__ cat_table, const float* __restrict__ pad_emb,
    float* __restrict__ xf, _Float16* __restrict__ xb, float* __restrict__ biasKey) {
    int t = blockIdx.x;             // token 0..16383
    int b = t >> 10, s = t & 1023;
    int j = b * 512 + (s & 511);
    int cat; float tm, f0;
    if (s < 512) { cat = ccat[j]; tm = ctime[j]; f0 = cf0[j]; }
    else         { cat = tcat[j]; tm = ttime[j]; f0 = tf0[j]; }
    bool pad = cat < 0;
    if (threadIdx.x == 0) biasKey[t] = pad ? -1e9f : 0.f;
    int c = cat < 0 ? 0 : cat;
    #pragma unroll
    for (int u = 0; u < 4; u++) {
        int d = threadIdx.x * 4 + u;   // 0..511
        float val;
        if (pad) val = pad_emb[d];
        else if (d < 256) val = cat_table[(long)c * 256 + d];
        else {
            float base = (d < 384) ? tm : f0;
            int i = (d < 384) ? (d - 256) : (d - 384);
            float ang = base / powf(1000.f, (float)i * (1.f / 128.f));
            val = (i & 1) ? cosf(ang) : sinf(ang);
        }
        long o = (long)t * 512 + d;
        xf[o] = val;
        xb[o] = (_Float16)val;
    }
}

// ------------------------------ layernorm ----------------------------------
__global__ __launch_bounds__(256) void layernorm_k(
    float* xf, _Float16* __restrict__ xb,
    const float* __restrict__ g, const float* __restrict__ beta) {
    long row = blockIdx.x;
    int tid = threadIdx.x;
    float* xr = xf + row * 512;
    float v0 = xr[tid], v1 = xr[tid + 256];
    float s = v0 + v1, q = v0 * v0 + v1 * v1;
    #pragma unroll
    for (int o = 32; o; o >>= 1) { s += __shfl_down(s, o); q += __shfl_down(q, o); }
    __shared__ float rs[4], rq[4];
    if ((tid & 63) == 0) { rs[tid >> 6] = s; rq[tid >> 6] = q; }
    __syncthreads();
    s = rs[0] + rs[1] + rs[2] + rs[3];
    q = rq[0] + rq[1] + rq[2] + rq[3];
    float mean = s * (1.f / 512.f);
    float var = q * (1.f / 512.f) - mean * mean;
    float rstd = rsqrtf(var + 1e-5f);
    float y0 = (v0 - mean) * rstd * g[tid] + beta[tid];
    float y1 = (v1 - mean) * rstd * g[tid + 256] + beta[tid + 256];
    xr[tid] = y0; xr[tid + 256] = y1;
    xb[row * 512 + tid] = (_Float16)y0;
    xb[row * 512 + tid + 256] = (_Float16)y1;
}

// ------------------------------- softmax -----------------------------------
// one block per row of 1024 f16 scores -> f16 probabilities
__global__ __launch_bounds__(256) void softmax_k(const _Float16* __restrict__ Sc, _Float16* __restrict__ P) {
    long row = blockIdx.x;
    const _Float16* sr = Sc + row * 1024;
    _Float16* pr = P + row * 1024;
    int tid = threadIdx.x;
    half4 hv = *reinterpret_cast<const half4*>(sr + tid * 4);
    float v[4];
    #pragma unroll
    for (int i = 0; i < 4; i++) v[i] = (float)hv[i];
    float m = fmaxf(fmaxf(v[0], v[1]), fmaxf(v[2], v[3]));
    #pragma unroll
    for (int o = 32; o; o >>= 1) m = fmaxf(m, __shfl_down(m, o));
    __shared__ float rm[4], rs[4];
    if ((tid & 63) == 0) rm[tid >> 6] = m;
    __syncthreads();
    m = fmaxf(fmaxf(rm[0], rm[1]), fmaxf(rm[2], rm[3]));
    float e[4], s = 0.f;
    #pragma unroll
    for (int i = 0; i < 4; i++) { e[i] = __expf(v[i] - m); s += e[i]; }
    #pragma unroll
    for (int o = 32; o; o >>= 1) s += __shfl_down(s, o);
    if ((tid & 63) == 0) rs[tid >> 6] = s;
    __syncthreads();
    s = rs[0] + rs[1] + rs[2] + rs[3];
    float inv = 1.f / s;
    half4 ov;
    #pragma unroll
    for (int i = 0; i < 4; i++) ov[i] = (_Float16)(e[i] * inv);
    *reinterpret_cast<half4*>(pr + tid * 4) = ov;
}

// ------------------------------ batched NT GEMM ----------------------------
// 128x128 tile, BK=32, 256 threads (4 waves 2x2, each 64x64 via 4x4 MFMA frags)
// Requires: M % 128 == 0, K % 32 == 0, all base ptrs + lda/ldb 16B-compatible.
__global__ __launch_bounds__(256) void gemm_nt(
    const _Float16* __restrict__ A, long lda, long sA1, long sA2,
    const _Float16* __restrict__ Bm, long ldb, long sB1, long sB2,
    float* Cf, _Float16* Cb, long ldc, long sC1, long sC2,
    const float* __restrict__ bias, long sb1, long sb2,
    const float* resid,
    int M, int N, int K, int Z2, float alpha, int relu) {
    int z = blockIdx.z;
    int z1 = z / Z2, z2 = z - z1 * Z2;
    A  += z1 * sA1 + z2 * sA2;
    Bm += z1 * sB1 + z2 * sB2;
    long coff = z1 * sC1 + z2 * sC2;
    if (bias) bias += z1 * sb1 + z2 * sb2;

    int m0 = blockIdx.y * 128;
    int n0 = blockIdx.x * 128;

    __shared__ __align__(16) _Float16 As[128][40];  // +8 pad: 2-way-max bank aliasing
    __shared__ __align__(16) _Float16 Bs[128][40];

    int tid = threadIdx.x;
    int lane = tid & 63;
    int w = tid >> 6;
    int wr = (w >> 1) << 6;    // wave row offset: 0/64
    int wc = (w & 1) << 6;     // wave col offset: 0/64

    f32x4 acc[4][4];
    #pragma unroll
    for (int i = 0; i < 4; i++)
        #pragma unroll
        for (int jj = 0; jj < 4; jj++) { acc[i][jj][0] = 0.f; acc[i][jj][1] = 0.f; acc[i][jj][2] = 0.f; acc[i][jj][3] = 0.f; }

    int fr = lane & 15;
    int fo = (lane >> 4) << 3;

    for (int kt = 0; kt < K; kt += 32) {
        #pragma unroll
        for (int i = 0; i < 2; i++) {
            int idx = tid + i * 256;            // 0..511
            int row = idx >> 2, ko = (idx & 3) << 3;
            uint4 av = *reinterpret_cast<const uint4*>(A + (long)(m0 + row) * lda + kt + ko);
            *reinterpret_cast<uint4*>(&As[row][ko]) = av;
            uint4 bv;
            if (n0 + row < N) bv = *reinterpret_cast<const uint4*>(Bm + (long)(n0 + row) * ldb + kt + ko);
            else { bv.x = 0; bv.y = 0; bv.z = 0; bv.w = 0; }
            *reinterpret_cast<uint4*>(&Bs[row][ko]) = bv;
        }
        __syncthreads();
        half8 af[4], bfv[4];
        #pragma unroll
        for (int m = 0; m < 4; m++) af[m] = *reinterpret_cast<const half8*>(&As[wr + m * 16 + fr][fo]);
        #pragma unroll
        for (int n = 0; n < 4; n++) bfv[n] = *reinterpret_cast<const half8*>(&Bs[wc + n * 16 + fr][fo]);
        #pragma unroll
        for (int m = 0; m < 4; m++)
            #pragma unroll
            for (int n = 0; n < 4; n++)
                acc[m][n] = __builtin_amdgcn_mfma_f32_16x16x32_f16(af[m], bfv[n], acc[m][n], 0, 0, 0);
        __syncthreads();
    }

    int fq = lane >> 4;
    #pragma unroll
    for (int m = 0; m < 4; m++) {
        #pragma unroll
        for (int jj = 0; jj < 4; jj++) {
            long row = m0 + wr + m * 16 + fq * 4 + jj;
            #pragma unroll
            for (int n = 0; n < 4; n++) {
                int col = n0 + wc + n * 16 + fr;
                if (col < N) {
                    float v = acc[m][n][jj] * alpha;
                    if (bias) v += bias[col];
                    long o = coff + row * ldc + col;
                    if (resid) v += resid[o];
                    if (relu) v = fmaxf(v, 0.f);
                    if (Cf) Cf[o] = v;
                    if (Cb) Cb[o] = (_Float16)v;
                }
            }
        }
    }
}

// ---------------------------------------------------------------------------
extern "C" void kernel_launch(void* const* d_in, const int* in_sizes, int n_in,
                              void* d_out, int out_size, void* d_ws, size_t ws_size,
                              hipStream_t stream) {
    const int Bn = 16, S = 1024, D = 512, H = 8, hd = 64, L = 2, DFF = 2048, NCAT = 1000, NCONT = 2048;
    const long M = (long)Bn * S;   // 16384 tokens

    const int*   ccat      = (const int*)d_in[0];
    const float* ctime     = (const float*)d_in[1];
    const float* cf0       = (const float*)d_in[2];
    const int*   tcat      = (const int*)d_in[3];
    const float* ttime     = (const float*)d_in[4];
    const float* tf0       = (const float*)d_in[5];
    const float* cat_table = (const float*)d_in[6];
    const float* cont_tab  = (const float*)d_in[7];
    const float* pad_emb   = (const float*)d_in[8];
    const float* Wq = (const float*)d_in[9];
    const float* bq = (const float*)d_in[10];
    const float* Wk = (const float*)d_in[11];
    const float* bk = (const float*)d_in[12];
    const float* Wv = (const float*)d_in[13];
    const float* bv = (const float*)d_in[14];
    const float* Wo = (const float*)d_in[15];
    const float* bo = (const float*)d_in[16];
    const float* ln1g = (const float*)d_in[17];
    const float* ln1b = (const float*)d_in[18];
    const float* ln2g = (const float*)d_in[19];
    const float* ln2b = (const float*)d_in[20];
    const float* W1 = (const float*)d_in[21];
    const float* b1 = (const float*)d_in[22];
    const float* W2 = (const float*)d_in[23];
    const float* b2 = (const float*)d_in[24];

    char* wsb = (char*)d_ws;
    size_t off = 0;
    auto alloc = [&](size_t bytes) -> void* {
        off = (off + 255) & ~(size_t)255;
        void* p = wsb + off; off += bytes; return p;
    };

    float*     xf      = (float*)alloc(M * D * 4);
    _Float16*  xb      = (_Float16*)alloc(M * D * 2);
    _Float16*  qb      = (_Float16*)alloc(M * D * 2);   // becomes attn-out in place
    _Float16*  kb      = (_Float16*)alloc(M * D * 2);
    _Float16*  vb      = (_Float16*)alloc(M * D * 2);
    _Float16*  vT      = (_Float16*)alloc(M * D * 2);
    float*     biasKey = (float*)alloc(M * 4);
    _Float16*  WqT  = (_Float16*)alloc((size_t)L * D * D * 2);
    _Float16*  WkT  = (_Float16*)alloc((size_t)L * D * D * 2);
    _Float16*  WvT  = (_Float16*)alloc((size_t)L * D * D * 2);
    _Float16*  WoT  = (_Float16*)alloc((size_t)L * D * D * 2);
    _Float16*  W1T  = (_Float16*)alloc((size_t)L * D * DFF * 2);
    _Float16*  W2T  = (_Float16*)alloc((size_t)L * DFF * D * 2);
    _Float16*  catT = (_Float16*)alloc((size_t)NCAT * 256 * 2);
    _Float16*  conT = (_Float16*)alloc((size_t)NCONT * 128 * 2);

    // scratch placement waterfall (ffh = FFN hidden, scores/P = attention chunk)
    size_t need_ffh = (size_t)M * DFF * 2;
    size_t perBatch = (size_t)H * S * S * 4;   // f16 scores + f16 P per batch
    size_t outBytes = (size_t)out_size * 4;
    _Float16 *ffh, *scoresBuf, *Pbuf;
    int CH;
    size_t offAl = (off + 255) & ~(size_t)255;
    if (offAl + need_ffh + perBatch <= ws_size) {
        ffh = (_Float16*)alloc(need_ffh);
        size_t rem = ws_size - ((off + 255) & ~(size_t)255);
        size_t ch = rem / perBatch;
        CH = ch > 16 ? 16 : (int)ch;
        scoresBuf = (_Float16*)alloc((size_t)CH * H * S * S * 2);
        Pbuf      = (_Float16*)alloc((size_t)CH * H * S * S * 2);
    } else {
        ffh = (_Float16*)d_out;   // d_out unused until final projections
        if (offAl + perBatch <= ws_size) {
            size_t rem = ws_size - offAl;
            size_t ch = rem / perBatch;
            CH = ch > 16 ? 16 : (int)ch;
            scoresBuf = (_Float16*)alloc((size_t)CH * H * S * S * 2);
            Pbuf      = (_Float16*)alloc((size_t)CH * H * S * S * 2);
        } else {
            size_t avail = outBytes - need_ffh;
            size_t ch = avail / perBatch;
            CH = ch < 1 ? 1 : (ch > 16 ? 16 : (int)ch);
            scoresBuf = (_Float16*)((char*)d_out + need_ffh);
            Pbuf = scoresBuf + (size_t)CH * H * S * S;
        }
    }

    auto gemm = [&](const _Float16* A, long lda, long sA1, long sA2,
                    const _Float16* Bm, long ldb, long sB1, long sB2,
                    float* Cf, _Float16* Cb, long ldc, long sC1, long sC2,
                    const float* bias, long sb1, long sb2,
                    const float* resid, int Mm, int Nn, int Kk,
                    int Z1, int Z2, float alpha, int relu) {
        dim3 g((Nn + 127) / 128, (Mm + 127) / 128, Z1 * Z2);
        gemm_nt<<<g, 256, 0, stream>>>(A, lda, sA1, sA2, Bm, ldb, sB1, sB2,
                                       Cf, Cb, ldc, sC1, sC2, bias, sb1, sb2,
                                       resid, Mm, Nn, Kk, Z2, alpha, relu);
    };

    dim3 tb(32, 8);
    // weights -> f16 transposed (NT form)
    tcast_k<<<dim3(D / 32, D / 32, L), tb, 0, stream>>>(Wq, WqT, D, D);
    tcast_k<<<dim3(D / 32, D / 32, L), tb, 0, stream>>>(Wk, WkT, D, D);
    tcast_k<<<dim3(D / 32, D / 32, L), tb, 0, stream>>>(Wv, WvT, D, D);
    tcast_k<<<dim3(D / 32, D / 32, L), tb, 0, stream>>>(Wo, WoT, D, D);
    tcast_k<<<dim3(DFF / 32, D / 32, L), tb, 0, stream>>>(W1, W1T, D, DFF);
    tcast_k<<<dim3(D / 32, DFF / 32, L), tb, 0, stream>>>(W2, W2T, DFF, D);
    cast_f32_f16_k<<<dim3((NCAT * 256 + 255) / 256), 256, 0, stream>>>(cat_table, catT, (long)NCAT * 256);
    cast_f32_f16_k<<<dim3((NCONT * 128 + 255) / 256), 256, 0, stream>>>(cont_tab, conT, (long)NCONT * 128);

    // embedding
    embed_k<<<dim3((unsigned)M), 128, 0, stream>>>(ccat, ctime, cf0, tcat, ttime, tf0,
                                                   cat_table, pad_emb, xf, xb, biasKey);

    const float inv_sqrt = 0.125f;   // 1/sqrt(64)
    for (int l = 0; l < L; l++) {
        // QKV projections
        gemm(xb, D, 0, 0, WqT + (size_t)l * D * D, D, 0, 0, nullptr, qb, D, 0, 0,
             bq + l * D, 0, 0, nullptr, (int)M, D, D, 1, 1, 1.f, 0);
        gemm(xb, D, 0, 0, WkT + (size_t)l * D * D, D, 0, 0, nullptr, kb, D, 0, 0,
             bk + l * D, 0, 0, nullptr, (int)M, D, D, 1, 1, 1.f, 0);
        gemm(xb, D, 0, 0, WvT + (size_t)l * D * D, D, 0, 0, nullptr, vb, D, 0, 0,
             bv + l * D, 0, 0, nullptr, (int)M, D, D, 1, 1, 1.f, 0);
        vtrans_k<<<dim3(32, 2, 128), tb, 0, stream>>>(vb, vT);

        // attention, chunked over batch
        for (int bc = 0; bc < Bn; bc += CH) {
            int Cc = (Bn - bc) < CH ? (Bn - bc) : CH;
            // scores[ci,h,q,k] = (Q . K) * inv_sqrt + biasKey[b,k]
            gemm(qb + (size_t)bc * S * D, D, (long)S * D, 64,
                 kb + (size_t)bc * S * D, D, (long)S * D, 64,
                 nullptr, scoresBuf, S, (long)H * S * S, (long)S * S,
                 biasKey + (size_t)bc * S, S, 0,
                 nullptr, S, S, hd, Cc, H, inv_sqrt, 0);
            softmax_k<<<dim3(Cc * H * S), 256, 0, stream>>>(scoresBuf, Pbuf);
            // O = P @ V  (writes back into qb rows of this chunk)
            gemm(Pbuf, S, (long)H * S * S, (long)S * S,
                 vT + (size_t)bc * H * hd * S, S, (long)H * hd * S, (long)hd * S,
                 nullptr, qb + (size_t)bc * S * D, D, (long)S * D, 64,
                 nullptr, 0, 0, nullptr, S, hd, S, Cc, H, 1.f, 0);
        }

        // out-proj + residual -> xf ; LN1 -> xf,xb
        gemm(qb, D, 0, 0, WoT + (size_t)l * D * D, D, 0, 0, xf, nullptr, D, 0, 0,
             bo + l * D, 0, 0, xf, (int)M, D, D, 1, 1, 1.f, 0);
        layernorm_k<<<dim3((unsigned)M), 256, 0, stream>>>(xf, xb, ln1g + l * D, ln1b + l * D);

        // FFN
        gemm(xb, D, 0, 0, W1T + (size_t)l * D * DFF, D, 0, 0, nullptr, ffh, DFF, 0, 0,
             b1 + l * DFF, 0, 0, nullptr, (int)M, DFF, D, 1, 1, 1.f, 1);
        gemm(ffh, DFF, 0, 0, W2T + (size_t)l * DFF * D, DFF, 0, 0, xf, nullptr, D, 0, 0,
             b2 + l * D, 0, 0, xf, (int)M, D, DFF, 1, 1, 1.f, 0);
        layernorm_k<<<dim3((unsigned)M), 256, 0, stream>>>(xf, xb, ln2g + l * D, ln2b + l * D);
    }

    // final projections from target half (rows 512..1023 of each batch)
    float* out_cat  = (float*)d_out;
    float* out_time = out_cat + (size_t)Bn * 512 * NCAT;
    float* out_f0   = out_time + (size_t)Bn * 512 * NCONT;
    gemm(xb + (size_t)512 * D, D, (long)S * D, 0,
         catT, 256, 0, 0,
         out_cat, nullptr, NCAT, (long)512 * NCAT, 0,
         nullptr, 0, 0, nullptr, 512, NCAT, 256, Bn, 1, 1.f, 0);
    gemm(xb + (size_t)512 * D + 256, D, (long)S * D, 0,
         conT, 128, 0, 0,
         out_time, nullptr, NCONT, (long)512 * NCONT, 0,
         nullptr, 0, 0, nullptr, 512, NCONT, 128, Bn, 1, 1.f, 0);
    gemm(xb + (size_t)512 * D + 384, D, (long)S * D, 0,
         conT, 128, 0, 0,
         out_f0, nullptr, NCONT, (long)512 * NCONT, 0,
         nullptr, 0, 0, nullptr, 512, NCONT, 128, Bn, 1, 1.f, 0);
}

// Round 2
// 1145.756 us; speedup vs baseline: 1.7398x; 1.7398x over previous
//
#include <hip/hip_runtime.h>

// ---------------------------------------------------------------------------
// SequenceModel: embed -> 2x transformer layer (flash attention) -> 3 projections
// GEMMs: C[M,N] = alpha * A[M,K] @ B[N,K]^T (+bias[col]) (+resid) (relu)
// A,B are _Float16; accum f32 via v_mfma_f32_16x16x32_f16.
// ---------------------------------------------------------------------------

typedef _Float16 half8 __attribute__((ext_vector_type(8)));
typedef _Float16 half4 __attribute__((ext_vector_type(4)));
typedef float f32x4 __attribute__((ext_vector_type(4)));

// ------------------------- elementwise cast f32->f16 -----------------------
__global__ void cast_f32_f16_k(const float* __restrict__ in, _Float16* __restrict__ out, long n) {
    long i = (long)blockIdx.x * blockDim.x + threadIdx.x;
    long stride = (long)gridDim.x * blockDim.x;
    for (; i < n; i += stride) out[i] = (_Float16)in[i];
}

// -------------- transpose+cast: in (Z,R,C) f32 -> out (Z,C,R) f16 ----------
__global__ void tcast_k(const float* __restrict__ in, _Float16* __restrict__ out, int R, int C) {
    __shared__ float tile[32][33];
    long z = blockIdx.z;
    const float* src = in + z * (long)R * C;
    _Float16* dst = out + z * (long)R * C;
    int c0 = blockIdx.x * 32, r0 = blockIdx.y * 32;
    for (int i = threadIdx.y; i < 32; i += 8)
        tile[i][threadIdx.x] = src[(long)(r0 + i) * C + c0 + threadIdx.x];
    __syncthreads();
    for (int i = threadIdx.y; i < 32; i += 8)
        dst[(long)(c0 + i) * R + r0 + threadIdx.x] = (_Float16)tile[threadIdx.x][i];
}

// -------- V transpose: v (B,S,H*hd) f16 -> vT (B*H, hd, S) f16 -------------
__global__ void vtrans_k(const _Float16* __restrict__ v, _Float16* __restrict__ vT) {
    __shared__ _Float16 tile[32][33];
    int bh = blockIdx.z; int b = bh >> 3, h = bh & 7;
    int s0 = blockIdx.x * 32, d0 = blockIdx.y * 32;
    const _Float16* src = v + ((long)b * 1024) * 512 + h * 64;  // [s][d], ld=512
    _Float16* dst = vT + (long)bh * 64 * 1024;                  // [d][s], ld=1024
    for (int i = threadIdx.y; i < 32; i += 8)
        tile[i][threadIdx.x] = src[(long)(s0 + i) * 512 + d0 + threadIdx.x];
    __syncthreads();
    for (int i = threadIdx.y; i < 32; i += 8)
        dst[(long)(d0 + i) * 1024 + s0 + threadIdx.x] = tile[threadIdx.x][i];
}

// ------------------------------- embedding ---------------------------------
__global__ __launch_bounds__(128) void embed_k(
    const int* __restrict__ ccat, const float* __restrict__ ctime, const float* __restrict__ cf0,
    const int* __restrict__ tcat, const float* __restrict__ ttime, const float* __restrict__ tf0,
    const float* __restrict__ cat_table, const float* __restrict__ pad_emb,
    float* __restrict__ xf, _Float16* __restrict__ xb, float* __restrict__ biasKey) {
    int t = blockIdx.x;             // token 0..16383
    int b = t >> 10, s = t & 1023;
    int j = b * 512 + (s & 511);
    int cat; float tm, f0;
    if (s < 512) { cat = ccat[j]; tm = ctime[j]; f0 = cf0[j]; }
    else         { cat = tcat[j]; tm = ttime[j]; f0 = tf0[j]; }
    bool pad = cat < 0;
    if (threadIdx.x == 0) biasKey[t] = pad ? -1e9f : 0.f;
    int c = cat < 0 ? 0 : cat;
    #pragma unroll
    for (int u = 0; u < 4; u++) {
        int d = threadIdx.x * 4 + u;   // 0..511
        float val;
        if (pad) val = pad_emb[d];
        else if (d < 256) val = cat_table[(long)c * 256 + d];
        else {
            float base = (d < 384) ? tm : f0;
            int i = (d < 384) ? (d - 256) : (d - 384);
            float ang = base / powf(1000.f, (float)i * (1.f / 128.f));
            val = (i & 1) ? cosf(ang) : sinf(ang);
        }
        long o = (long)t * 512 + d;
        xf[o] = val;
        xb[o] = (_Float16)val;
    }
}

// ------------------------------ layernorm ----------------------------------
__global__ __launch_bounds__(256) void layernorm_k(
    float* xf, _Float16* __restrict__ xb,
    const float* __restrict__ g, const float* __restrict__ beta) {
    long row = blockIdx.x;
    int tid = threadIdx.x;
    float* xr = xf + row * 512;
    float v0 = xr[tid], v1 = xr[tid + 256];
    float s = v0 + v1, q = v0 * v0 + v1 * v1;
    #pragma unroll
    for (int o = 32; o; o >>= 1) { s += __shfl_down(s, o); q += __shfl_down(q, o); }
    __shared__ float rs[4], rq[4];
    if ((tid & 63) == 0) { rs[tid >> 6] = s; rq[tid >> 6] = q; }
    __syncthreads();
    s = rs[0] + rs[1] + rs[2] + rs[3];
    q = rq[0] + rq[1] + rq[2] + rq[3];
    float mean = s * (1.f / 512.f);
    float var = q * (1.f / 512.f) - mean * mean;
    float rstd = rsqrtf(var + 1e-5f);
    float y0 = (v0 - mean) * rstd * g[tid] + beta[tid];
    float y1 = (v1 - mean) * rstd * g[tid + 256] + beta[tid + 256];
    xr[tid] = y0; xr[tid + 256] = y1;
    xb[row * 512 + tid] = (_Float16)y0;
    xb[row * 512 + tid + 256] = (_Float16)y1;
}

// ------------------------------ flash attention ----------------------------
// grid (B*H, S/64), 256 threads = 4 waves, wave w handles 16 q rows.
// Per K-tile (128 keys): swapped QK^T (col=q), in-register online softmax,
// P repacked to LDS (half4 packs, 272B row stride -> bank-uniform), PV MFMA.
__global__ __launch_bounds__(256) void flash_k(
    const _Float16* __restrict__ Q, const _Float16* __restrict__ K,
    const _Float16* __restrict__ VT, const float* __restrict__ biasKey,
    _Float16* __restrict__ O) {
    const int S = 1024, D = 512;
    int bh = blockIdx.x; int b = bh >> 3, h = bh & 7;
    int qt = blockIdx.y;
    int tid = threadIdx.x, w = tid >> 6, lane = tid & 63;
    int g = lane >> 4, q15 = lane & 15;

    __shared__ __align__(16) _Float16 Ks[128][72];    // stride 144B = 9*16
    __shared__ __align__(16) _Float16 VTs[64][136];   // stride 272B = 17*16
    __shared__ __align__(16) _Float16 Ps[4][16][136];
    __shared__ __align__(16) float biasLds[1024];

    // stage key-pad bias for this batch
    {
        const float* bsrc = biasKey + (long)b * S;
        *(f32x4*)&biasLds[tid * 4] = *(const f32x4*)&bsrc[tid * 4];
    }

    // Q fragments (held in registers for the whole kernel)
    int qrow = qt * 64 + w * 16 + q15;
    const _Float16* qp = Q + ((long)(b * S + qrow)) * D + h * 64 + g * 8;
    half8 qf[2];
    qf[0] = *(const half8*)(qp);
    qf[1] = *(const half8*)(qp + 32);

    f32x4 acc_o[4];
    #pragma unroll
    for (int i = 0; i < 4; i++)
        #pragma unroll
        for (int r = 0; r < 4; r++) acc_o[i][r] = 0.f;
    float m_run = -1e30f, l_run = 0.f;

    const _Float16* kbase = K + ((long)b * S) * D + h * 64;
    const _Float16* vbase = VT + (long)bh * 64 * S;

    for (int kt = 0; kt < 8; kt++) {
        __syncthreads();   // previous tile fully consumed
        // stage K tile [128 keys][64 d]
        #pragma unroll
        for (int i = 0; i < 4; i++) {
            int c = tid + i * 256;
            int row = c >> 3, cc = c & 7;
            uint4 v = *(const uint4*)(kbase + (long)(kt * 128 + row) * D + cc * 8);
            *(uint4*)&Ks[row][cc * 8] = v;
        }
        // stage V^T tile [64 d][128 keys]
        #pragma unroll
        for (int i = 0; i < 4; i++) {
            int c = tid + i * 256;
            int row = c >> 4, cc = c & 15;
            uint4 v = *(const uint4*)(vbase + (long)row * S + kt * 128 + cc * 8);
            *(uint4*)&VTs[row][cc * 8] = v;
        }
        __syncthreads();

        // QK^T swapped: acc[mf] col=q15, row(key) = 16*mf + 4*g + reg
        f32x4 acc[8];
        #pragma unroll
        for (int mf = 0; mf < 8; mf++)
            #pragma unroll
            for (int r = 0; r < 4; r++) acc[mf][r] = 0.f;
        #pragma unroll
        for (int kk = 0; kk < 2; kk++)
            #pragma unroll
            for (int mf = 0; mf < 8; mf++) {
                half8 kf = *(const half8*)&Ks[mf * 16 + q15][kk * 32 + g * 8];
                acc[mf] = __builtin_amdgcn_mfma_f32_16x16x32_f16(kf, qf[kk], acc[mf], 0, 0, 0);
            }

        // scale + bias, row max (this lane owns q=q15's scores for 32 keys)
        float mt = -1e30f;
        #pragma unroll
        for (int mf = 0; mf < 8; mf++) {
            f32x4 b4 = *(const f32x4*)&biasLds[kt * 128 + mf * 16 + g * 4];
            #pragma unroll
            for (int r = 0; r < 4; r++) {
                float sv = acc[mf][r] * 0.125f + b4[r];
                acc[mf][r] = sv;
                mt = fmaxf(mt, sv);
            }
        }
        mt = fmaxf(mt, __shfl_xor(mt, 16));
        mt = fmaxf(mt, __shfl_xor(mt, 32));
        float m_new = fmaxf(m_run, mt);
        float scale = __expf(m_run - m_new);
        float rsum = 0.f;
        #pragma unroll
        for (int mf = 0; mf < 8; mf++)
            #pragma unroll
            for (int r = 0; r < 4; r++) {
                float p = __expf(acc[mf][r] - m_new);
                acc[mf][r] = p;
                rsum += p;
            }
        rsum += __shfl_xor(rsum, 16);
        rsum += __shfl_xor(rsum, 32);
        l_run = l_run * scale + rsum;
        m_run = m_new;

        // rescale O: its row q = 4*g + r; scale lives at lane (lane&15)==q
        float sc[4];
        #pragma unroll
        for (int r = 0; r < 4; r++) sc[r] = __shfl(scale, g * 4 + r);
        #pragma unroll
        for (int nf = 0; nf < 4; nf++)
            #pragma unroll
            for (int r = 0; r < 4; r++) acc_o[nf][r] *= sc[r];

        // P -> LDS: regs are 4 consecutive keys -> half4 pack, b64 store
        #pragma unroll
        for (int mf = 0; mf < 8; mf++) {
            half4 h4;
            #pragma unroll
            for (int r = 0; r < 4; r++) h4[r] = (_Float16)acc[mf][r];
            *(half4*)&Ps[w][q15][mf * 16 + g * 4] = h4;
        }

        // PV: O[16q][64d] += P[16][128] @ V[128][64]
        #pragma unroll
        for (int kk = 0; kk < 4; kk++) {
            half8 pa = *(const half8*)&Ps[w][q15][kk * 32 + g * 8];
            #pragma unroll
            for (int nf = 0; nf < 4; nf++) {
                half8 vf = *(const half8*)&VTs[nf * 16 + q15][kk * 32 + g * 8];
                acc_o[nf] = __builtin_amdgcn_mfma_f32_16x16x32_f16(pa, vf, acc_o[nf], 0, 0, 0);
            }
        }
    }

    // epilogue: O /= l, store f16
    float linv = 1.f / l_run;
    float lv[4];
    #pragma unroll
    for (int r = 0; r < 4; r++) lv[r] = __shfl(linv, g * 4 + r);
    _Float16* obase = O + ((long)(b * S + qt * 64 + w * 16)) * D + h * 64;
    #pragma unroll
    for (int nf = 0; nf < 4; nf++)
        #pragma unroll
        for (int r = 0; r < 4; r++) {
            int row = g * 4 + r;
            obase[(long)row * D + nf * 16 + q15] = (_Float16)(acc_o[nf][r] * lv[r]);
        }
}

// ------------------------------ batched NT GEMM ----------------------------
__global__ __launch_bounds__(256) void gemm_nt(
    const _Float16* __restrict__ A, long lda, long sA1, long sA2,
    const _Float16* __restrict__ Bm, long ldb, long sB1, long sB2,
    float* Cf, _Float16* Cb, long ldc, long sC1, long sC2,
    const float* __restrict__ bias, long sb1, long sb2,
    const float* resid,
    int M, int N, int K, int Z2, float alpha, int relu) {
    int z = blockIdx.z;
    int z1 = z / Z2, z2 = z - z1 * Z2;
    A  += z1 * sA1 + z2 * sA2;
    Bm += z1 * sB1 + z2 * sB2;
    long coff = z1 * sC1 + z2 * sC2;
    if (bias) bias += z1 * sb1 + z2 * sb2;

    int m0 = blockIdx.y * 128;
    int n0 = blockIdx.x * 128;

    __shared__ __align__(16) _Float16 As[128][40];
    __shared__ __align__(16) _Float16 Bs[128][40];

    int tid = threadIdx.x;
    int lane = tid & 63;
    int w = tid >> 6;
    int wr = (w >> 1) << 6;
    int wc = (w & 1) << 6;

    f32x4 acc[4][4];
    #pragma unroll
    for (int i = 0; i < 4; i++)
        #pragma unroll
        for (int jj = 0; jj < 4; jj++) { acc[i][jj][0] = 0.f; acc[i][jj][1] = 0.f; acc[i][jj][2] = 0.f; acc[i][jj][3] = 0.f; }

    int fr = lane & 15;
    int fo = (lane >> 4) << 3;

    for (int kt = 0; kt < K; kt += 32) {
        #pragma unroll
        for (int i = 0; i < 2; i++) {
            int idx = tid + i * 256;
            int row = idx >> 2, ko = (idx & 3) << 3;
            uint4 av = *reinterpret_cast<const uint4*>(A + (long)(m0 + row) * lda + kt + ko);
            *reinterpret_cast<uint4*>(&As[row][ko]) = av;
            uint4 bv;
            if (n0 + row < N) bv = *reinterpret_cast<const uint4*>(Bm + (long)(n0 + row) * ldb + kt + ko);
            else { bv.x = 0; bv.y = 0; bv.z = 0; bv.w = 0; }
            *reinterpret_cast<uint4*>(&Bs[row][ko]) = bv;
        }
        __syncthreads();
        half8 af[4], bfv[4];
        #pragma unroll
        for (int m = 0; m < 4; m++) af[m] = *reinterpret_cast<const half8*>(&As[wr + m * 16 + fr][fo]);
        #pragma unroll
        for (int n = 0; n < 4; n++) bfv[n] = *reinterpret_cast<const half8*>(&Bs[wc + n * 16 + fr][fo]);
        #pragma unroll
        for (int m = 0; m < 4; m++)
            #pragma unroll
            for (int n = 0; n < 4; n++)
                acc[m][n] = __builtin_amdgcn_mfma_f32_16x16x32_f16(af[m], bfv[n], acc[m][n], 0, 0, 0);
        __syncthreads();
    }

    int fq = lane >> 4;
    #pragma unroll
    for (int m = 0; m < 4; m++) {
        #pragma unroll
        for (int jj = 0; jj < 4; jj++) {
            long row = m0 + wr + m * 16 + fq * 4 + jj;
            #pragma unroll
            for (int n = 0; n < 4; n++) {
                int col = n0 + wc + n * 16 + fr;
                if (col < N) {
                    float v = acc[m][n][jj] * alpha;
                    if (bias) v += bias[col];
                    long o = coff + row * ldc + col;
                    if (resid) v += resid[o];
                    if (relu) v = fmaxf(v, 0.f);
                    if (Cf) Cf[o] = v;
                    if (Cb) Cb[o] = (_Float16)v;
                }
            }
        }
    }
}

// ---------------------------------------------------------------------------
extern "C" void kernel_launch(void* const* d_in, const int* in_sizes, int n_in,
                              void* d_out, int out_size, void* d_ws, size_t ws_size,
                              hipStream_t stream) {
    const int Bn = 16, S = 1024, D = 512, H = 8, hd = 64, L = 2, DFF = 2048, NCAT = 1000, NCONT = 2048;
    const long M = (long)Bn * S;

    const int*   ccat      = (const int*)d_in[0];
    const float* ctime     = (const float*)d_in[1];
    const float* cf0       = (const float*)d_in[2];
    const int*   tcat      = (const int*)d_in[3];
    const float* ttime     = (const float*)d_in[4];
    const float* tf0       = (const float*)d_in[5];
    const float* cat_table = (const float*)d_in[6];
    const float* cont_tab  = (const float*)d_in[7];
    const float* pad_emb   = (const float*)d_in[8];
    const float* Wq = (const float*)d_in[9];
    const float* bq = (const float*)d_in[10];
    const float* Wk = (const float*)d_in[11];
    const float* bk = (const float*)d_in[12];
    const float* Wv = (const float*)d_in[13];
    const float* bv = (const float*)d_in[14];
    const float* Wo = (const float*)d_in[15];
    const float* bo = (const float*)d_in[16];
    const float* ln1g = (const float*)d_in[17];
    const float* ln1b = (const float*)d_in[18];
    const float* ln2g = (const float*)d_in[19];
    const float* ln2b = (const float*)d_in[20];
    const float* W1 = (const float*)d_in[21];
    const float* b1 = (const float*)d_in[22];
    const float* W2 = (const float*)d_in[23];
    const float* b2 = (const float*)d_in[24];

    char* wsb = (char*)d_ws;
    size_t off = 0;
    auto alloc = [&](size_t bytes) -> void* {
        off = (off + 255) & ~(size_t)255;
        void* p = wsb + off; off += bytes; return p;
    };

    float*     xf      = (float*)alloc(M * D * 4);
    _Float16*  xb      = (_Float16*)alloc(M * D * 2);
    _Float16*  qb      = (_Float16*)alloc(M * D * 2);
    _Float16*  kb      = (_Float16*)alloc(M * D * 2);
    _Float16*  vb      = (_Float16*)alloc(M * D * 2);
    _Float16*  vT      = (_Float16*)alloc(M * D * 2);
    _Float16*  ob      = (_Float16*)alloc(M * D * 2);   // attention output
    float*     biasKey = (float*)alloc(M * 4);
    _Float16*  WqT  = (_Float16*)alloc((size_t)L * D * D * 2);
    _Float16*  WkT  = (_Float16*)alloc((size_t)L * D * D * 2);
    _Float16*  WvT  = (_Float16*)alloc((size_t)L * D * D * 2);
    _Float16*  WoT  = (_Float16*)alloc((size_t)L * D * D * 2);
    _Float16*  W1T  = (_Float16*)alloc((size_t)L * D * DFF * 2);
    _Float16*  W2T  = (_Float16*)alloc((size_t)L * DFF * D * 2);
    _Float16*  catT = (_Float16*)alloc((size_t)NCAT * 256 * 2);
    _Float16*  conT = (_Float16*)alloc((size_t)NCONT * 128 * 2);

    // FFN hidden: ws if it fits, else front of d_out (unused until final proj)
    size_t need_ffh = (size_t)M * DFF * 2;
    _Float16* ffh;
    size_t offAl = (off + 255) & ~(size_t)255;
    if (offAl + need_ffh <= ws_size) ffh = (_Float16*)alloc(need_ffh);
    else ffh = (_Float16*)d_out;

    auto gemm = [&](const _Float16* A, long lda, long sA1, long sA2,
                    const _Float16* Bm, long ldb, long sB1, long sB2,
                    float* Cf, _Float16* Cb, long ldc, long sC1, long sC2,
                    const float* bias, long sb1, long sb2,
                    const float* resid, int Mm, int Nn, int Kk,
                    int Z1, int Z2, float alpha, int relu) {
        dim3 g((Nn + 127) / 128, (Mm + 127) / 128, Z1 * Z2);
        gemm_nt<<<g, 256, 0, stream>>>(A, lda, sA1, sA2, Bm, ldb, sB1, sB2,
                                       Cf, Cb, ldc, sC1, sC2, bias, sb1, sb2,
                                       resid, Mm, Nn, Kk, Z2, alpha, relu);
    };

    dim3 tb(32, 8);
    tcast_k<<<dim3(D / 32, D / 32, L), tb, 0, stream>>>(Wq, WqT, D, D);
    tcast_k<<<dim3(D / 32, D / 32, L), tb, 0, stream>>>(Wk, WkT, D, D);
    tcast_k<<<dim3(D / 32, D / 32, L), tb, 0, stream>>>(Wv, WvT, D, D);
    tcast_k<<<dim3(D / 32, D / 32, L), tb, 0, stream>>>(Wo, WoT, D, D);
    tcast_k<<<dim3(DFF / 32, D / 32, L), tb, 0, stream>>>(W1, W1T, D, DFF);
    tcast_k<<<dim3(D / 32, DFF / 32, L), tb, 0, stream>>>(W2, W2T, DFF, D);
    cast_f32_f16_k<<<dim3((NCAT * 256 + 255) / 256), 256, 0, stream>>>(cat_table, catT, (long)NCAT * 256);
    cast_f32_f16_k<<<dim3((NCONT * 128 + 255) / 256), 256, 0, stream>>>(cont_tab, conT, (long)NCONT * 128);

    embed_k<<<dim3((unsigned)M), 128, 0, stream>>>(ccat, ctime, cf0, tcat, ttime, tf0,
                                                   cat_table, pad_emb, xf, xb, biasKey);

    for (int l = 0; l < L; l++) {
        gemm(xb, D, 0, 0, WqT + (size_t)l * D * D, D, 0, 0, nullptr, qb, D, 0, 0,
             bq + l * D, 0, 0, nullptr, (int)M, D, D, 1, 1, 1.f, 0);
        gemm(xb, D, 0, 0, WkT + (size_t)l * D * D, D, 0, 0, nullptr, kb, D, 0, 0,
             bk + l * D, 0, 0, nullptr, (int)M, D, D, 1, 1, 1.f, 0);
        gemm(xb, D, 0, 0, WvT + (size_t)l * D * D, D, 0, 0, nullptr, vb, D, 0, 0,
             bv + l * D, 0, 0, nullptr, (int)M, D, D, 1, 1, 1.f, 0);
        vtrans_k<<<dim3(32, 2, Bn * H), tb, 0, stream>>>(vb, vT);

        // fused flash attention: qb,kb,vT -> ob
        flash_k<<<dim3(Bn * H, S / 64), 256, 0, stream>>>(qb, kb, vT, biasKey, ob);

        gemm(ob, D, 0, 0, WoT + (size_t)l * D * D, D, 0, 0, xf, nullptr, D, 0, 0,
             bo + l * D, 0, 0, xf, (int)M, D, D, 1, 1, 1.f, 0);
        layernorm_k<<<dim3((unsigned)M), 256, 0, stream>>>(xf, xb, ln1g + l * D, ln1b + l * D);

        gemm(xb, D, 0, 0, W1T + (size_t)l * D * DFF, D, 0, 0, nullptr, ffh, DFF, 0, 0,
             b1 + l * DFF, 0, 0, nullptr, (int)M, DFF, D, 1, 1, 1.f, 1);
        gemm(ffh, DFF, 0, 0, W2T + (size_t)l * DFF * D, DFF, 0, 0, xf, nullptr, D, 0, 0,
             b2 + l * D, 0, 0, xf, (int)M, D, DFF, 1, 1, 1.f, 0);
        layernorm_k<<<dim3((unsigned)M), 256, 0, stream>>>(xf, xb, ln2g + l * D, ln2b + l * D);
    }

    float* out_cat  = (float*)d_out;
    float* out_time = out_cat + (size_t)Bn * 512 * NCAT;
    float* out_f0   = out_time + (size_t)Bn * 512 * NCONT;
    gemm(xb + (size_t)512 * D, D, (long)S * D, 0,
         catT, 256, 0, 0,
         out_cat, nullptr, NCAT, (long)512 * NCAT, 0,
         nullptr, 0, 0, nullptr, 512, NCAT, 256, Bn, 1, 1.f, 0);
    gemm(xb + (size_t)512 * D + 256, D, (long)S * D, 0,
         conT, 128, 0, 0,
         out_time, nullptr, NCONT, (long)512 * NCONT, 0,
         nullptr, 0, 0, nullptr, 512, NCONT, 128, Bn, 1, 1.f, 0);
    gemm(xb + (size_t)512 * D + 384, D, (long)S * D, 0,
         conT, 128, 0, 0,
         out_f0, nullptr, NCONT, (long)512 * NCONT, 0,
         nullptr, 0, 0, nullptr, 512, NCONT, 128, Bn, 1, 1.f, 0);
}

// Round 3
// 926.713 us; speedup vs baseline: 2.1510x; 1.2364x over previous
//
#include <hip/hip_runtime.h>

// ---------------------------------------------------------------------------
// SequenceModel: embed -> 2x transformer layer (flash attention) -> 3 projections
// GEMMs: C[M,N] = alpha * A[M,K] @ B[N,K]^T (+bias[col]) (+resid) (relu)
// A,B are _Float16; accum f32 via v_mfma_f32_16x16x32_f16.
// gemm_nt: dbuf LDS + global_load_lds(16B) + slot-swizzle + XCD-chunked grid.
// ---------------------------------------------------------------------------

typedef _Float16 half8 __attribute__((ext_vector_type(8)));
typedef _Float16 half4 __attribute__((ext_vector_type(4)));
typedef float f32x4 __attribute__((ext_vector_type(4)));

__device__ __forceinline__ void gl2lds16(const _Float16* g, _Float16* l) {
    __builtin_amdgcn_global_load_lds(
        (const __attribute__((address_space(1))) void*)g,
        (__attribute__((address_space(3))) void*)l, 16, 0, 0);
}

// ------------------- cast f32->f16 with zero-pad tail ----------------------
__global__ void cast_f32_f16_k(const float* __restrict__ in, _Float16* __restrict__ out,
                               long nsrc, long ntot) {
    long i = (long)blockIdx.x * blockDim.x + threadIdx.x;
    long stride = (long)gridDim.x * blockDim.x;
    for (; i < ntot; i += stride) out[i] = i < nsrc ? (_Float16)in[i] : (_Float16)0.f;
}

// ------ transpose+cast: in (Z,R,C) f32 -> out + z*zs + (rowoff+c)*R f16 ----
__global__ void tcast_k(const float* __restrict__ in, _Float16* __restrict__ out,
                        int R, int C, long zs, int rowoff) {
    __shared__ float tile[32][33];
    long z = blockIdx.z;
    const float* src = in + z * (long)R * C;
    _Float16* dst = out + z * zs + (long)rowoff * R;
    int c0 = blockIdx.x * 32, r0 = blockIdx.y * 32;
    for (int i = threadIdx.y; i < 32; i += 8)
        tile[i][threadIdx.x] = src[(long)(r0 + i) * C + c0 + threadIdx.x];
    __syncthreads();
    for (int i = threadIdx.y; i < 32; i += 8)
        dst[(long)(c0 + i) * R + r0 + threadIdx.x] = (_Float16)tile[threadIdx.x][i];
}

// --------------------------- bias concat q|k|v ------------------------------
__global__ void bcat_k(const float* __restrict__ bq, const float* __restrict__ bk,
                       const float* __restrict__ bv, float* __restrict__ out, int L) {
    int i = blockIdx.x * 256 + threadIdx.x;
    if (i >= L * 1536) return;
    int l = i / 1536, j = i - l * 1536;
    float v = j < 512 ? bq[l * 512 + j] : (j < 1024 ? bk[l * 512 + j - 512] : bv[l * 512 + j - 1024]);
    out[i] = v;
}

// -------- V transpose: qkv[...,1024+h*64+d] -> vT (B*H, hd, S) f16 ---------
__global__ void vtrans_k(const _Float16* __restrict__ qkv, _Float16* __restrict__ vT) {
    __shared__ _Float16 tile[32][33];
    int bh = blockIdx.z; int b = bh >> 3, h = bh & 7;
    int s0 = blockIdx.x * 32, d0 = blockIdx.y * 32;
    const _Float16* src = qkv + ((long)b * 1024) * 1536 + 1024 + h * 64;  // [s][d], ld=1536
    _Float16* dst = vT + (long)bh * 64 * 1024;                            // [d][s], ld=1024
    for (int i = threadIdx.y; i < 32; i += 8)
        tile[i][threadIdx.x] = src[(long)(s0 + i) * 1536 + d0 + threadIdx.x];
    __syncthreads();
    for (int i = threadIdx.y; i < 32; i += 8)
        dst[(long)(d0 + i) * 1024 + s0 + threadIdx.x] = tile[threadIdx.x][i];
}

// ------------------------------- embedding ---------------------------------
__global__ __launch_bounds__(128) void embed_k(
    const int* __restrict__ ccat, const float* __restrict__ ctime, const float* __restrict__ cf0,
    const int* __restrict__ tcat, const float* __restrict__ ttime, const float* __restrict__ tf0,
    const float* __restrict__ cat_table, const float* __restrict__ pad_emb,
    float* __restrict__ xf, _Float16* __restrict__ xb, float* __restrict__ biasKey) {
    int t = blockIdx.x;             // token 0..16383
    int b = t >> 10, s = t & 1023;
    int j = b * 512 + (s & 511);
    int cat; float tm, f0;
    if (s < 512) { cat = ccat[j]; tm = ctime[j]; f0 = cf0[j]; }
    else         { cat = tcat[j]; tm = ttime[j]; f0 = tf0[j]; }
    bool pad = cat < 0;
    if (threadIdx.x == 0) biasKey[t] = pad ? -1e9f : 0.f;
    int c = cat < 0 ? 0 : cat;
    #pragma unroll
    for (int u = 0; u < 4; u++) {
        int d = threadIdx.x * 4 + u;   // 0..511
        float val;
        if (pad) val = pad_emb[d];
        else if (d < 256) val = cat_table[(long)c * 256 + d];
        else {
            float base = (d < 384) ? tm : f0;
            int i = (d < 384) ? (d - 256) : (d - 384);
            float ang = base / powf(1000.f, (float)i * (1.f / 128.f));
            val = (i & 1) ? cosf(ang) : sinf(ang);
        }
        long o = (long)t * 512 + d;
        xf[o] = val;
        xb[o] = (_Float16)val;
    }
}

// ------------------------------ layernorm ----------------------------------
__global__ __launch_bounds__(256) void layernorm_k(
    float* xf, _Float16* __restrict__ xb,
    const float* __restrict__ g, const float* __restrict__ beta) {
    long row = blockIdx.x;
    int tid = threadIdx.x;
    float* xr = xf + row * 512;
    float v0 = xr[tid], v1 = xr[tid + 256];
    float s = v0 + v1, q = v0 * v0 + v1 * v1;
    #pragma unroll
    for (int o = 32; o; o >>= 1) { s += __shfl_down(s, o); q += __shfl_down(q, o); }
    __shared__ float rs[4], rq[4];
    if ((tid & 63) == 0) { rs[tid >> 6] = s; rq[tid >> 6] = q; }
    __syncthreads();
    s = rs[0] + rs[1] + rs[2] + rs[3];
    q = rq[0] + rq[1] + rq[2] + rq[3];
    float mean = s * (1.f / 512.f);
    float var = q * (1.f / 512.f) - mean * mean;
    float rstd = rsqrtf(var + 1e-5f);
    float y0 = (v0 - mean) * rstd * g[tid] + beta[tid];
    float y1 = (v1 - mean) * rstd * g[tid + 256] + beta[tid + 256];
    xr[tid] = y0; xr[tid + 256] = y1;
    xb[row * 512 + tid] = (_Float16)y0;
    xb[row * 512 + tid + 256] = (_Float16)y1;
}

// ------------------------------ flash attention ----------------------------
// grid (B*H, S/64), 256 threads = 4 waves, wave w handles 16 q rows.
// Q,K live in qkv (ld=1536, K at +512); V^T in vT (ld=1024).
__global__ __launch_bounds__(256) void flash_k(
    const _Float16* __restrict__ QKV, const _Float16* __restrict__ VT,
    const float* __restrict__ biasKey, _Float16* __restrict__ O) {
    const int S = 1024, D = 512, LDQ = 1536;
    int bh = blockIdx.x; int b = bh >> 3, h = bh & 7;
    int qt = blockIdx.y;
    int tid = threadIdx.x, w = tid >> 6, lane = tid & 63;
    int g = lane >> 4, q15 = lane & 15;

    __shared__ __align__(16) _Float16 Ks[128][72];    // stride 144B
    __shared__ __align__(16) _Float16 VTs[64][136];   // stride 272B
    __shared__ __align__(16) _Float16 Ps[4][16][136];
    __shared__ __align__(16) float biasLds[1024];

    {
        const float* bsrc = biasKey + (long)b * S;
        *(f32x4*)&biasLds[tid * 4] = *(const f32x4*)&bsrc[tid * 4];
    }

    int qrow = qt * 64 + w * 16 + q15;
    const _Float16* qp = QKV + ((long)(b * S + qrow)) * LDQ + h * 64 + g * 8;
    half8 qf[2];
    qf[0] = *(const half8*)(qp);
    qf[1] = *(const half8*)(qp + 32);

    f32x4 acc_o[4];
    #pragma unroll
    for (int i = 0; i < 4; i++)
        #pragma unroll
        for (int r = 0; r < 4; r++) acc_o[i][r] = 0.f;
    float m_run = -1e30f, l_run = 0.f;

    const _Float16* kbase = QKV + 512 + ((long)b * S) * LDQ + h * 64;
    const _Float16* vbase = VT + (long)bh * 64 * S;

    for (int kt = 0; kt < 8; kt++) {
        __syncthreads();
        #pragma unroll
        for (int i = 0; i < 4; i++) {
            int c = tid + i * 256;
            int row = c >> 3, cc = c & 7;
            uint4 v = *(const uint4*)(kbase + (long)(kt * 128 + row) * LDQ + cc * 8);
            *(uint4*)&Ks[row][cc * 8] = v;
        }
        #pragma unroll
        for (int i = 0; i < 4; i++) {
            int c = tid + i * 256;
            int row = c >> 4, cc = c & 15;
            uint4 v = *(const uint4*)(vbase + (long)row * S + kt * 128 + cc * 8);
            *(uint4*)&VTs[row][cc * 8] = v;
        }
        __syncthreads();

        f32x4 acc[8];
        #pragma unroll
        for (int mf = 0; mf < 8; mf++)
            #pragma unroll
            for (int r = 0; r < 4; r++) acc[mf][r] = 0.f;
        #pragma unroll
        for (int kk = 0; kk < 2; kk++)
            #pragma unroll
            for (int mf = 0; mf < 8; mf++) {
                half8 kf = *(const half8*)&Ks[mf * 16 + q15][kk * 32 + g * 8];
                acc[mf] = __builtin_amdgcn_mfma_f32_16x16x32_f16(kf, qf[kk], acc[mf], 0, 0, 0);
            }

        float mt = -1e30f;
        #pragma unroll
        for (int mf = 0; mf < 8; mf++) {
            f32x4 b4 = *(const f32x4*)&biasLds[kt * 128 + mf * 16 + g * 4];
            #pragma unroll
            for (int r = 0; r < 4; r++) {
                float sv = acc[mf][r] * 0.125f + b4[r];
                acc[mf][r] = sv;
                mt = fmaxf(mt, sv);
            }
        }
        mt = fmaxf(mt, __shfl_xor(mt, 16));
        mt = fmaxf(mt, __shfl_xor(mt, 32));
        float m_new = fmaxf(m_run, mt);
        float scale = __expf(m_run - m_new);
        float rsum = 0.f;
        #pragma unroll
        for (int mf = 0; mf < 8; mf++)
            #pragma unroll
            for (int r = 0; r < 4; r++) {
                float p = __expf(acc[mf][r] - m_new);
                acc[mf][r] = p;
                rsum += p;
            }
        rsum += __shfl_xor(rsum, 16);
        rsum += __shfl_xor(rsum, 32);
        l_run = l_run * scale + rsum;
        m_run = m_new;

        float sc[4];
        #pragma unroll
        for (int r = 0; r < 4; r++) sc[r] = __shfl(scale, g * 4 + r);
        #pragma unroll
        for (int nf = 0; nf < 4; nf++)
            #pragma unroll
            for (int r = 0; r < 4; r++) acc_o[nf][r] *= sc[r];

        #pragma unroll
        for (int mf = 0; mf < 8; mf++) {
            half4 h4;
            #pragma unroll
            for (int r = 0; r < 4; r++) h4[r] = (_Float16)acc[mf][r];
            *(half4*)&Ps[w][q15][mf * 16 + g * 4] = h4;
        }

        #pragma unroll
        for (int kk = 0; kk < 4; kk++) {
            half8 pa = *(const half8*)&Ps[w][q15][kk * 32 + g * 8];
            #pragma unroll
            for (int nf = 0; nf < 4; nf++) {
                half8 vf = *(const half8*)&VTs[nf * 16 + q15][kk * 32 + g * 8];
                acc_o[nf] = __builtin_amdgcn_mfma_f32_16x16x32_f16(pa, vf, acc_o[nf], 0, 0, 0);
            }
        }
    }

    float linv = 1.f / l_run;
    float lv[4];
    #pragma unroll
    for (int r = 0; r < 4; r++) lv[r] = __shfl(linv, g * 4 + r);
    _Float16* obase = O + ((long)(b * S + qt * 64 + w * 16)) * D + h * 64;
    #pragma unroll
    for (int nf = 0; nf < 4; nf++)
        #pragma unroll
        for (int r = 0; r < 4; r++) {
            int row = g * 4 + r;
            obase[(long)row * D + nf * 16 + q15] = (_Float16)(acc_o[nf][r] * lv[r]);
        }
}

// ------------------------------ batched NT GEMM ----------------------------
// 128x128 tile, BK=32, dbuf LDS, global_load_lds 16B, slot-swizzled layout.
// Requires M%128==0, K%32==0, B buffer rows >= ceil128(N) (pad B if needed).
__global__ __launch_bounds__(256) void gemm_nt(
    const _Float16* __restrict__ A, long lda, long sA1, long sA2,
    const _Float16* __restrict__ Bm, long ldb, long sB1, long sB2,
    float* Cf, _Float16* Cb, long ldc, long sC1, long sC2,
    const float* __restrict__ bias, long sb1, long sb2,
    const float* resid,
    int M, int N, int K, int Z2, float alpha, int relu) {
    int z = blockIdx.z;
    int z1 = z / Z2, z2 = z - z1 * Z2;
    A  += z1 * sA1 + z2 * sA2;
    Bm += z1 * sB1 + z2 * sB2;
    long coff = z1 * sC1 + z2 * sC2;
    if (bias) bias += z1 * sb1 + z2 * sb2;

    // XCD-chunked bijective block swizzle over (y,x)
    int gx = gridDim.x;
    int nwg = gx * gridDim.y;
    int bid = blockIdx.y * gx + blockIdx.x;
    int q = nwg >> 3, r = nwg & 7;
    int xcd = bid & 7, ii = bid >> 3;
    int swz = (xcd < r ? xcd * (q + 1) : r * (q + 1) + (xcd - r) * q) + ii;
    int m0 = (swz / gx) * 128;
    int n0 = (swz % gx) * 128;

    __shared__ __align__(16) _Float16 As[2][128 * 32];
    __shared__ __align__(16) _Float16 Bs[2][128 * 32];

    int tid = threadIdx.x;
    int lane = tid & 63;
    int w = tid >> 6;
    int wr = (w >> 1) << 6;
    int wc = (w & 1) << 6;

    f32x4 acc[4][4];
    #pragma unroll
    for (int i = 0; i < 4; i++)
        #pragma unroll
        for (int jj = 0; jj < 4; jj++) { acc[i][jj][0] = 0.f; acc[i][jj][1] = 0.f; acc[i][jj][2] = 0.f; acc[i][jj][3] = 0.f; }

    int fr = lane & 15;
    int g = lane >> 4;
    int rs8 = (g ^ (fr & 3)) * 8;   // swizzled 16B-slot (involution with store side)

    // stage: 16B per lane; LDS dest linear (wave-base + lane*16); source slot
    // pre-swizzled so swizzled ds_read sees logical layout (rule: both sides).
    auto stage = [&](int buf, int kt) {
        #pragma unroll
        for (int i = 0; i < 2; i++) {
            int idx = tid + i * 256;          // 0..511
            int row = idx >> 2, s = idx & 3;
            int sg = s ^ (row & 3);
            gl2lds16(A + (long)(m0 + row) * lda + kt * 32 + sg * 8, &As[buf][idx * 8]);
            gl2lds16(Bm + (long)(n0 + row) * ldb + kt * 32 + sg * 8, &Bs[buf][idx * 8]);
        }
    };

    int nk = K >> 5;
    stage(0, 0);
    __syncthreads();

    int cur = 0;
    for (int kt = 0; kt < nk; kt++) {
        if (kt + 1 < nk) stage(cur ^ 1, kt + 1);
        half8 af[4], bfv[4];
        #pragma unroll
        for (int m = 0; m < 4; m++) af[m] = *(const half8*)&As[cur][(wr + m * 16 + fr) * 32 + rs8];
        #pragma unroll
        for (int n = 0; n < 4; n++) bfv[n] = *(const half8*)&Bs[cur][(wc + n * 16 + fr) * 32 + rs8];
        #pragma unroll
        for (int m = 0; m < 4; m++)
            #pragma unroll
            for (int n = 0; n < 4; n++)
                acc[m][n] = __builtin_amdgcn_mfma_f32_16x16x32_f16(af[m], bfv[n], acc[m][n], 0, 0, 0);
        __syncthreads();   // drains vmcnt (staged tile ready) + protects dbuf
        cur ^= 1;
    }

    int fq = lane >> 4;
    #pragma unroll
    for (int m = 0; m < 4; m++) {
        #pragma unroll
        for (int jj = 0; jj < 4; jj++) {
            long row = m0 + wr + m * 16 + fq * 4 + jj;
            #pragma unroll
            for (int n = 0; n < 4; n++) {
                int col = n0 + wc + n * 16 + fr;
                if (col < N) {
                    float v = acc[m][n][jj] * alpha;
                    if (bias) v += bias[col];
                    long o = coff + row * ldc + col;
                    if (resid) v += resid[o];
                    if (relu) v = fmaxf(v, 0.f);
                    if (Cf) Cf[o] = v;
                    if (Cb) Cb[o] = (_Float16)v;
                }
            }
        }
    }
}

// ---------------------------------------------------------------------------
extern "C" void kernel_launch(void* const* d_in, const int* in_sizes, int n_in,
                              void* d_out, int out_size, void* d_ws, size_t ws_size,
                              hipStream_t stream) {
    const int Bn = 16, S = 1024, D = 512, H = 8, L = 2, DFF = 2048, NCAT = 1000, NCONT = 2048;
    const long M = (long)Bn * S;

    const int*   ccat      = (const int*)d_in[0];
    const float* ctime     = (const float*)d_in[1];
    const float* cf0       = (const float*)d_in[2];
    const int*   tcat      = (const int*)d_in[3];
    const float* ttime     = (const float*)d_in[4];
    const float* tf0       = (const float*)d_in[5];
    const float* cat_table = (const float*)d_in[6];
    const float* cont_tab  = (const float*)d_in[7];
    const float* pad_emb   = (const float*)d_in[8];
    const float* Wq = (const float*)d_in[9];
    const float* bq = (const float*)d_in[10];
    const float* Wk = (const float*)d_in[11];
    const float* bk = (const float*)d_in[12];
    const float* Wv = (const float*)d_in[13];
    const float* bv = (const float*)d_in[14];
    const float* Wo = (const float*)d_in[15];
    const float* bo = (const float*)d_in[16];
    const float* ln1g = (const float*)d_in[17];
    const float* ln1b = (const float*)d_in[18];
    const float* ln2g = (const float*)d_in[19];
    const float* ln2b = (const float*)d_in[20];
    const float* W1 = (const float*)d_in[21];
    const float* b1 = (const float*)d_in[22];
    const float* W2 = (const float*)d_in[23];
    const float* b2 = (const float*)d_in[24];

    char* wsb = (char*)d_ws;
    size_t off = 0;
    auto alloc = [&](size_t bytes) -> void* {
        off = (off + 255) & ~(size_t)255;
        void* p = wsb + off; off += bytes; return p;
    };

    float*     xf      = (float*)alloc(M * D * 4);
    _Float16*  xb      = (_Float16*)alloc(M * D * 2);
    _Float16*  qkv     = (_Float16*)alloc(M * 3 * D * 2);   // [M][1536] q|k|v
    _Float16*  vT      = (_Float16*)alloc(M * D * 2);
    _Float16*  ob      = (_Float16*)alloc(M * D * 2);
    float*     biasKey = (float*)alloc(M * 4);
    _Float16*  WqkvT = (_Float16*)alloc((size_t)L * 3 * D * D * 2);
    float*     bqkv  = (float*)alloc((size_t)L * 3 * D * 4);
    _Float16*  WoT  = (_Float16*)alloc((size_t)L * D * D * 2);
    _Float16*  W1T  = (_Float16*)alloc((size_t)L * D * DFF * 2);
    _Float16*  W2T  = (_Float16*)alloc((size_t)L * DFF * D * 2);
    _Float16*  catT = (_Float16*)alloc((size_t)1024 * 256 * 2);   // padded to 1024 rows
    _Float16*  conT = (_Float16*)alloc((size_t)NCONT * 128 * 2);

    size_t need_ffh = (size_t)M * DFF * 2;
    _Float16* ffh;
    size_t offAl = (off + 255) & ~(size_t)255;
    if (offAl + need_ffh <= ws_size) ffh = (_Float16*)alloc(need_ffh);
    else ffh = (_Float16*)d_out;

    auto gemm = [&](const _Float16* A, long lda, long sA1, long sA2,
                    const _Float16* Bm, long ldb, long sB1, long sB2,
                    float* Cf, _Float16* Cb, long ldc, long sC1, long sC2,
                    const float* bias, long sb1, long sb2,
                    const float* resid, int Mm, int Nn, int Kk,
                    int Z1, int Z2, float alpha, int relu) {
        dim3 gdim((Nn + 127) / 128, (Mm + 127) / 128, Z1 * Z2);
        gemm_nt<<<gdim, 256, 0, stream>>>(A, lda, sA1, sA2, Bm, ldb, sB1, sB2,
                                          Cf, Cb, ldc, sC1, sC2, bias, sb1, sb2,
                                          resid, Mm, Nn, Kk, Z2, alpha, relu);
    };

    dim3 tb(32, 8);
    // QKV weights concat -> [L][1536][512] NT form
    tcast_k<<<dim3(D / 32, D / 32, L), tb, 0, stream>>>(Wq, WqkvT, D, D, (long)3 * D * D, 0);
    tcast_k<<<dim3(D / 32, D / 32, L), tb, 0, stream>>>(Wk, WqkvT, D, D, (long)3 * D * D, D);
    tcast_k<<<dim3(D / 32, D / 32, L), tb, 0, stream>>>(Wv, WqkvT, D, D, (long)3 * D * D, 2 * D);
    bcat_k<<<dim3((L * 1536 + 255) / 256), 256, 0, stream>>>(bq, bk, bv, bqkv, L);
    tcast_k<<<dim3(D / 32, D / 32, L), tb, 0, stream>>>(Wo, WoT, D, D, (long)D * D, 0);
    tcast_k<<<dim3(DFF / 32, D / 32, L), tb, 0, stream>>>(W1, W1T, D, DFF, (long)D * DFF, 0);
    tcast_k<<<dim3(D / 32, DFF / 32, L), tb, 0, stream>>>(W2, W2T, DFF, D, (long)DFF * D, 0);
    cast_f32_f16_k<<<dim3(512), 256, 0, stream>>>(cat_table, catT, (long)NCAT * 256, (long)1024 * 256);
    cast_f32_f16_k<<<dim3(512), 256, 0, stream>>>(cont_tab, conT, (long)NCONT * 128, (long)NCONT * 128);

    embed_k<<<dim3((unsigned)M), 128, 0, stream>>>(ccat, ctime, cf0, tcat, ttime, tf0,
                                                   cat_table, pad_emb, xf, xb, biasKey);

    for (int l = 0; l < L; l++) {
        // fused QKV projection: [M][1536]
        gemm(xb, D, 0, 0, WqkvT + (size_t)l * 3 * D * D, D, 0, 0, nullptr, qkv, 3 * D, 0, 0,
             bqkv + (size_t)l * 3 * D, 0, 0, nullptr, (int)M, 3 * D, D, 1, 1, 1.f, 0);
        vtrans_k<<<dim3(32, 2, Bn * H), tb, 0, stream>>>(qkv, vT);

        flash_k<<<dim3(Bn * H, S / 64), 256, 0, stream>>>(qkv, vT, biasKey, ob);

        gemm(ob, D, 0, 0, WoT + (size_t)l * D * D, D, 0, 0, xf, nullptr, D, 0, 0,
             bo + l * D, 0, 0, xf, (int)M, D, D, 1, 1, 1.f, 0);
        layernorm_k<<<dim3((unsigned)M), 256, 0, stream>>>(xf, xb, ln1g + l * D, ln1b + l * D);

        gemm(xb, D, 0, 0, W1T + (size_t)l * D * DFF, D, 0, 0, nullptr, ffh, DFF, 0, 0,
             b1 + l * DFF, 0, 0, nullptr, (int)M, DFF, D, 1, 1, 1.f, 1);
        gemm(ffh, DFF, 0, 0, W2T + (size_t)l * DFF * D, DFF, 0, 0, xf, nullptr, D, 0, 0,
             b2 + l * D, 0, 0, xf, (int)M, D, DFF, 1, 1, 1.f, 0);
        layernorm_k<<<dim3((unsigned)M), 256, 0, stream>>>(xf, xb, ln2g + l * D, ln2b + l * D);
    }

    float* out_cat  = (float*)d_out;
    float* out_time = out_cat + (size_t)Bn * 512 * NCAT;
    float* out_f0   = out_time + (size_t)Bn * 512 * NCONT;
    gemm(xb + (size_t)512 * D, D, (long)S * D, 0,
         catT, 256, 0, 0,
         out_cat, nullptr, NCAT, (long)512 * NCAT, 0,
         nullptr, 0, 0, nullptr, 512, NCAT, 256, Bn, 1, 1.f, 0);
    gemm(xb + (size_t)512 * D + 256, D, (long)S * D, 0,
         conT, 128, 0, 0,
         out_time, nullptr, NCONT, (long)512 * NCONT, 0,
         nullptr, 0, 0, nullptr, 512, NCONT, 128, Bn, 1, 1.f, 0);
    gemm(xb + (size_t)512 * D + 384, D, (long)S * D, 0,
         conT, 128, 0, 0,
         out_f0, nullptr, NCONT, (long)512 * NCONT, 0,
         nullptr, 0, 0, nullptr, 512, NCONT, 128, Bn, 1, 1.f, 0);
}

// Round 4
// 921.067 us; speedup vs baseline: 2.1642x; 1.0061x over previous
//
#include <hip/hip_runtime.h>

// ---------------------------------------------------------------------------
// SequenceModel: embed -> 2x transformer layer (flash attention) -> 3 projections
// GEMMs: C[M,N] = alpha * A[M,K] @ B[N,K]^T (+bias[col]) (+resid) (relu)
// A,B are _Float16; accum f32 via v_mfma_f32_16x16x32_f16.
// gemm_nt: dbuf LDS + global_load_lds(16B) + slot-swizzle + XCD-chunked grid.
// flash_k: KVBLK=64 dbuf, gload_lds staging, exp2 softmax, defer-max, setprio.
// ---------------------------------------------------------------------------

typedef _Float16 half8 __attribute__((ext_vector_type(8)));
typedef _Float16 half4 __attribute__((ext_vector_type(4)));
typedef float f32x4 __attribute__((ext_vector_type(4)));

__device__ __forceinline__ void gl2lds16(const _Float16* g, _Float16* l) {
    __builtin_amdgcn_global_load_lds(
        (const __attribute__((address_space(1))) void*)g,
        (__attribute__((address_space(3))) void*)l, 16, 0, 0);
}

// ------------------- cast f32->f16 with zero-pad tail ----------------------
__global__ void cast_f32_f16_k(const float* __restrict__ in, _Float16* __restrict__ out,
                               long nsrc, long ntot) {
    long i = (long)blockIdx.x * blockDim.x + threadIdx.x;
    long stride = (long)gridDim.x * blockDim.x;
    for (; i < ntot; i += stride) out[i] = i < nsrc ? (_Float16)in[i] : (_Float16)0.f;
}

// ------ transpose+cast: in (Z,R,C) f32 -> out + z*zs + (rowoff+c)*R f16 ----
__global__ void tcast_k(const float* __restrict__ in, _Float16* __restrict__ out,
                        int R, int C, long zs, int rowoff) {
    __shared__ float tile[32][33];
    long z = blockIdx.z;
    const float* src = in + z * (long)R * C;
    _Float16* dst = out + z * zs + (long)rowoff * R;
    int c0 = blockIdx.x * 32, r0 = blockIdx.y * 32;
    for (int i = threadIdx.y; i < 32; i += 8)
        tile[i][threadIdx.x] = src[(long)(r0 + i) * C + c0 + threadIdx.x];
    __syncthreads();
    for (int i = threadIdx.y; i < 32; i += 8)
        dst[(long)(c0 + i) * R + r0 + threadIdx.x] = (_Float16)tile[threadIdx.x][i];
}

// --------------------------- bias concat q|k|v ------------------------------
__global__ void bcat_k(const float* __restrict__ bq, const float* __restrict__ bk,
                       const float* __restrict__ bv, float* __restrict__ out, int L) {
    int i = blockIdx.x * 256 + threadIdx.x;
    if (i >= L * 1536) return;
    int l = i / 1536, j = i - l * 1536;
    float v = j < 512 ? bq[l * 512 + j] : (j < 1024 ? bk[l * 512 + j - 512] : bv[l * 512 + j - 1024]);
    out[i] = v;
}

// -------- V transpose: qkv[...,1024+h*64+d] -> vT (B*H, hd, S) f16 ---------
__global__ void vtrans_k(const _Float16* __restrict__ qkv, _Float16* __restrict__ vT) {
    __shared__ _Float16 tile[32][33];
    int bh = blockIdx.z; int b = bh >> 3, h = bh & 7;
    int s0 = blockIdx.x * 32, d0 = blockIdx.y * 32;
    const _Float16* src = qkv + ((long)b * 1024) * 1536 + 1024 + h * 64;  // [s][d], ld=1536
    _Float16* dst = vT + (long)bh * 64 * 1024;                            // [d][s], ld=1024
    for (int i = threadIdx.y; i < 32; i += 8)
        tile[i][threadIdx.x] = src[(long)(s0 + i) * 1536 + d0 + threadIdx.x];
    __syncthreads();
    for (int i = threadIdx.y; i < 32; i += 8)
        dst[(long)(d0 + i) * 1024 + s0 + threadIdx.x] = tile[threadIdx.x][i];
}

// ------------------------------- embedding ---------------------------------
__global__ __launch_bounds__(128) void embed_k(
    const int* __restrict__ ccat, const float* __restrict__ ctime, const float* __restrict__ cf0,
    const int* __restrict__ tcat, const float* __restrict__ ttime, const float* __restrict__ tf0,
    const float* __restrict__ cat_table, const float* __restrict__ pad_emb,
    float* __restrict__ xf, _Float16* __restrict__ xb, float* __restrict__ biasKey) {
    int t = blockIdx.x;             // token 0..16383
    int b = t >> 10, s = t & 1023;
    int j = b * 512 + (s & 511);
    int cat; float tm, f0;
    if (s < 512) { cat = ccat[j]; tm = ctime[j]; f0 = cf0[j]; }
    else         { cat = tcat[j]; tm = ttime[j]; f0 = tf0[j]; }
    bool pad = cat < 0;
    if (threadIdx.x == 0) biasKey[t] = pad ? -1e9f : 0.f;
    int c = cat < 0 ? 0 : cat;
    #pragma unroll
    for (int u = 0; u < 4; u++) {
        int d = threadIdx.x * 4 + u;   // 0..511
        float val;
        if (pad) val = pad_emb[d];
        else if (d < 256) val = cat_table[(long)c * 256 + d];
        else {
            float base = (d < 384) ? tm : f0;
            int i = (d < 384) ? (d - 256) : (d - 384);
            float ang = base / powf(1000.f, (float)i * (1.f / 128.f));
            val = (i & 1) ? cosf(ang) : sinf(ang);
        }
        long o = (long)t * 512 + d;
        xf[o] = val;
        xb[o] = (_Float16)val;
    }
}

// ------------------------------ layernorm ----------------------------------
__global__ __launch_bounds__(256) void layernorm_k(
    float* xf, _Float16* __restrict__ xb,
    const float* __restrict__ g, const float* __restrict__ beta) {
    long row = blockIdx.x;
    int tid = threadIdx.x;
    float* xr = xf + row * 512;
    float v0 = xr[tid], v1 = xr[tid + 256];
    float s = v0 + v1, q = v0 * v0 + v1 * v1;
    #pragma unroll
    for (int o = 32; o; o >>= 1) { s += __shfl_down(s, o); q += __shfl_down(q, o); }
    __shared__ float rs[4], rq[4];
    if ((tid & 63) == 0) { rs[tid >> 6] = s; rq[tid >> 6] = q; }
    __syncthreads();
    s = rs[0] + rs[1] + rs[2] + rs[3];
    q = rq[0] + rq[1] + rq[2] + rq[3];
    float mean = s * (1.f / 512.f);
    float var = q * (1.f / 512.f) - mean * mean;
    float rstd = rsqrtf(var + 1e-5f);
    float y0 = (v0 - mean) * rstd * g[tid] + beta[tid];
    float y1 = (v1 - mean) * rstd * g[tid + 256] + beta[tid + 256];
    xr[tid] = y0; xr[tid + 256] = y1;
    xb[row * 512 + tid] = (_Float16)y0;
    xb[row * 512 + tid + 256] = (_Float16)y1;
}

// ------------------------------ flash attention ----------------------------
// grid (B*H, S/64), 256 threads = 4 waves, wave w handles 16 q rows.
// KVBLK=64, double-buffered K/V via global_load_lds with XOR-slot source
// swizzle (linear LDS dest). exp2-domain softmax, defer-max THR=8 (log2),
// setprio(1) around MFMA clusters. One barrier per K-tile.
__global__ __launch_bounds__(256, 3) void flash_k(
    const _Float16* __restrict__ QKV, const _Float16* __restrict__ VT,
    const float* __restrict__ biasKey, _Float16* __restrict__ O) {
    const int S = 1024, D = 512, LDQ = 1536, NT = 16;
    int bh = blockIdx.x; int b = bh >> 3, h = bh & 7;
    int qt = blockIdx.y;
    int tid = threadIdx.x, w = tid >> 6, lane = tid & 63;
    int g = lane >> 4, q15 = lane & 15;

    __shared__ __align__(16) _Float16 Ks[2][64 * 64];   // [kv][d], 8 slots/row
    __shared__ __align__(16) _Float16 VTs[2][64 * 64];  // [d][kv], 8 slots/row
    __shared__ __align__(16) _Float16 Ps[4][16][72];
    __shared__ __align__(16) float biasLds[1024];

    {   // bias * log2(e) (0 or -1.44e9)
        const float* bsrc = biasKey + (long)b * S;
        f32x4 bv4 = *(const f32x4*)&bsrc[tid * 4];
        #pragma unroll
        for (int r = 0; r < 4; r++) bv4[r] *= 1.442695041f;
        *(f32x4*)&biasLds[tid * 4] = bv4;
    }

    // Q fragments, pre-scaled by 0.125*log2(e)
    int qrow = qt * 64 + w * 16 + q15;
    const _Float16* qp = QKV + ((long)(b * S + qrow)) * LDQ + h * 64 + g * 8;
    half8 qf[2];
    qf[0] = *(const half8*)(qp);
    qf[1] = *(const half8*)(qp + 32);
    const _Float16 qsc = (_Float16)0.1803368801f;
    #pragma unroll
    for (int kk = 0; kk < 2; kk++)
        #pragma unroll
        for (int i = 0; i < 8; i++) qf[kk][i] *= qsc;

    const _Float16* kbase = QKV + 512 + ((long)b * S) * LDQ + h * 64;
    const _Float16* vbase = VT + (long)bh * 64 * S;

    // async stage of K/V tile kt into buffer buf; LDS linear, source slot
    // XOR-swizzled so swizzled ds_read recovers logical layout (rule #21).
    auto stage = [&](int buf, int kt) {
        #pragma unroll
        for (int i = 0; i < 2; i++) {
            int c = tid + i * 256;         // 0..511 slots
            int row = c >> 3, p = c & 7;
            int s = p ^ (row & 7);
            gl2lds16(kbase + (long)(kt * 64 + row) * LDQ + s * 8, &Ks[buf][c * 8]);
            gl2lds16(vbase + (long)row * S + kt * 64 + s * 8, &VTs[buf][c * 8]);
        }
    };

    f32x4 acc_o[4];
    #pragma unroll
    for (int i = 0; i < 4; i++)
        #pragma unroll
        for (int r = 0; r < 4; r++) acc_o[i][r] = 0.f;
    float m_run = -1e30f, l_run = 0.f;

    stage(0, 0);
    int cur = 0;
    for (int kt = 0; kt < NT; kt++) {
        __syncthreads();   // implicit vmcnt(0): tile cur ready; buf^1 free
        if (kt + 1 < NT) stage(cur ^ 1, kt + 1);   // prefetch rides under compute

        // QK^T swapped: lane owns q=q15, keys 16*mf+4*g+r
        f32x4 acc[4];
        #pragma unroll
        for (int mf = 0; mf < 4; mf++)
            #pragma unroll
            for (int r = 0; r < 4; r++) acc[mf][r] = 0.f;
        __builtin_amdgcn_s_setprio(1);
        #pragma unroll
        for (int kk = 0; kk < 2; kk++)
            #pragma unroll
            for (int mf = 0; mf < 4; mf++) {
                int row = mf * 16 + q15;
                half8 kf = *(const half8*)&Ks[cur][row * 64 + (((kk * 4 + g) ^ (row & 7)) * 8)];
                acc[mf] = __builtin_amdgcn_mfma_f32_16x16x32_f16(kf, qf[kk], acc[mf], 0, 0, 0);
            }
        __builtin_amdgcn_s_setprio(0);

        // bias add + row max (log2 domain)
        float mt = -1e30f;
        #pragma unroll
        for (int mf = 0; mf < 4; mf++) {
            f32x4 b4 = *(const f32x4*)&biasLds[kt * 64 + mf * 16 + g * 4];
            #pragma unroll
            for (int r = 0; r < 4; r++) {
                float sv = acc[mf][r] + b4[r];
                acc[mf][r] = sv;
                mt = fmaxf(mt, sv);
            }
        }
        mt = fmaxf(mt, __shfl_xor(mt, 16));
        mt = fmaxf(mt, __shfl_xor(mt, 32));

        float rsum = 0.f;
        if (__all((int)(mt - m_run <= 8.f))) {
            // deferred: keep old max; P bounded by 2^8
            #pragma unroll
            for (int mf = 0; mf < 4; mf++)
                #pragma unroll
                for (int r = 0; r < 4; r++) {
                    float p = exp2f(acc[mf][r] - m_run);
                    acc[mf][r] = p; rsum += p;
                }
        } else {
            float m_new = fmaxf(m_run, mt);
            float scale = exp2f(m_run - m_new);
            #pragma unroll
            for (int mf = 0; mf < 4; mf++)
                #pragma unroll
                for (int r = 0; r < 4; r++) {
                    float p = exp2f(acc[mf][r] - m_new);
                    acc[mf][r] = p; rsum += p;
                }
            float sc[4];
            #pragma unroll
            for (int r = 0; r < 4; r++) sc[r] = __shfl(scale, g * 4 + r);
            #pragma unroll
            for (int nf = 0; nf < 4; nf++)
                #pragma unroll
                for (int r = 0; r < 4; r++) acc_o[nf][r] *= sc[r];
            l_run *= scale;
            m_run = m_new;
        }
        rsum += __shfl_xor(rsum, 16);
        rsum += __shfl_xor(rsum, 32);
        l_run += rsum;

        // P -> LDS (half4 packs; bank-ideal)
        #pragma unroll
        for (int mf = 0; mf < 4; mf++) {
            half4 h4;
            #pragma unroll
            for (int r = 0; r < 4; r++) h4[r] = (_Float16)acc[mf][r];
            *(half4*)&Ps[w][q15][mf * 16 + g * 4] = h4;
        }

        // PV: O[16q][64d] += P[16][64] @ V[64][64]
        __builtin_amdgcn_s_setprio(1);
        #pragma unroll
        for (int kk = 0; kk < 2; kk++) {
            half8 pa = *(const half8*)&Ps[w][q15][kk * 32 + g * 8];
            #pragma unroll
            for (int nf = 0; nf < 4; nf++) {
                int row = nf * 16 + q15;
                half8 vf = *(const half8*)&VTs[cur][row * 64 + (((kk * 4 + g) ^ (row & 7)) * 8)];
                acc_o[nf] = __builtin_amdgcn_mfma_f32_16x16x32_f16(pa, vf, acc_o[nf], 0, 0, 0);
            }
        }
        __builtin_amdgcn_s_setprio(0);
        cur ^= 1;
    }

    float linv = 1.f / l_run;
    float lv[4];
    #pragma unroll
    for (int r = 0; r < 4; r++) lv[r] = __shfl(linv, g * 4 + r);
    _Float16* obase = O + ((long)(b * S + qt * 64 + w * 16)) * D + h * 64;
    #pragma unroll
    for (int nf = 0; nf < 4; nf++)
        #pragma unroll
        for (int r = 0; r < 4; r++) {
            int row = g * 4 + r;
            obase[(long)row * D + nf * 16 + q15] = (_Float16)(acc_o[nf][r] * lv[r]);
        }
}

// ------------------------------ batched NT GEMM ----------------------------
// 128x128 tile, BK=32, dbuf LDS, global_load_lds 16B, slot-swizzled layout.
// Requires M%128==0, K%32==0, B buffer rows >= ceil128(N) (pad B if needed).
__global__ __launch_bounds__(256) void gemm_nt(
    const _Float16* __restrict__ A, long lda, long sA1, long sA2,
    const _Float16* __restrict__ Bm, long ldb, long sB1, long sB2,
    float* Cf, _Float16* Cb, long ldc, long sC1, long sC2,
    const float* __restrict__ bias, long sb1, long sb2,
    const float* resid,
    int M, int N, int K, int Z2, float alpha, int relu) {
    int z = blockIdx.z;
    int z1 = z / Z2, z2 = z - z1 * Z2;
    A  += z1 * sA1 + z2 * sA2;
    Bm += z1 * sB1 + z2 * sB2;
    long coff = z1 * sC1 + z2 * sC2;
    if (bias) bias += z1 * sb1 + z2 * sb2;

    // XCD-chunked bijective block swizzle over (y,x)
    int gx = gridDim.x;
    int nwg = gx * gridDim.y;
    int bid = blockIdx.y * gx + blockIdx.x;
    int q = nwg >> 3, r = nwg & 7;
    int xcd = bid & 7, ii = bid >> 3;
    int swz = (xcd < r ? xcd * (q + 1) : r * (q + 1) + (xcd - r) * q) + ii;
    int m0 = (swz / gx) * 128;
    int n0 = (swz % gx) * 128;

    __shared__ __align__(16) _Float16 As[2][128 * 32];
    __shared__ __align__(16) _Float16 Bs[2][128 * 32];

    int tid = threadIdx.x;
    int lane = tid & 63;
    int w = tid >> 6;
    int wr = (w >> 1) << 6;
    int wc = (w & 1) << 6;

    f32x4 acc[4][4];
    #pragma unroll
    for (int i = 0; i < 4; i++)
        #pragma unroll
        for (int jj = 0; jj < 4; jj++) { acc[i][jj][0] = 0.f; acc[i][jj][1] = 0.f; acc[i][jj][2] = 0.f; acc[i][jj][3] = 0.f; }

    int fr = lane & 15;
    int g = lane >> 4;
    int rs8 = (g ^ (fr & 3)) * 8;   // swizzled 16B-slot (involution with store side)

    auto stage = [&](int buf, int kt) {
        #pragma unroll
        for (int i = 0; i < 2; i++) {
            int idx = tid + i * 256;          // 0..511
            int row = idx >> 2, s = idx & 3;
            int sg = s ^ (row & 3);
            gl2lds16(A + (long)(m0 + row) * lda + kt * 32 + sg * 8, &As[buf][idx * 8]);
            gl2lds16(Bm + (long)(n0 + row) * ldb + kt * 32 + sg * 8, &Bs[buf][idx * 8]);
        }
    };

    int nk = K >> 5;
    stage(0, 0);
    __syncthreads();

    int cur = 0;
    for (int kt = 0; kt < nk; kt++) {
        if (kt + 1 < nk) stage(cur ^ 1, kt + 1);
        half8 af[4], bfv[4];
        #pragma unroll
        for (int m = 0; m < 4; m++) af[m] = *(const half8*)&As[cur][(wr + m * 16 + fr) * 32 + rs8];
        #pragma unroll
        for (int n = 0; n < 4; n++) bfv[n] = *(const half8*)&Bs[cur][(wc + n * 16 + fr) * 32 + rs8];
        #pragma unroll
        for (int m = 0; m < 4; m++)
            #pragma unroll
            for (int n = 0; n < 4; n++)
                acc[m][n] = __builtin_amdgcn_mfma_f32_16x16x32_f16(af[m], bfv[n], acc[m][n], 0, 0, 0);
        __syncthreads();   // drains vmcnt (staged tile ready) + protects dbuf
        cur ^= 1;
    }

    int fq = lane >> 4;
    #pragma unroll
    for (int m = 0; m < 4; m++) {
        #pragma unroll
        for (int jj = 0; jj < 4; jj++) {
            long row = m0 + wr + m * 16 + fq * 4 + jj;
            #pragma unroll
            for (int n = 0; n < 4; n++) {
                int col = n0 + wc + n * 16 + fr;
                if (col < N) {
                    float v = acc[m][n][jj] * alpha;
                    if (bias) v += bias[col];
                    long o = coff + row * ldc + col;
                    if (resid) v += resid[o];
                    if (relu) v = fmaxf(v, 0.f);
                    if (Cf) Cf[o] = v;
                    if (Cb) Cb[o] = (_Float16)v;
                }
            }
        }
    }
}

// ---------------------------------------------------------------------------
extern "C" void kernel_launch(void* const* d_in, const int* in_sizes, int n_in,
                              void* d_out, int out_size, void* d_ws, size_t ws_size,
                              hipStream_t stream) {
    const int Bn = 16, S = 1024, D = 512, H = 8, L = 2, DFF = 2048, NCAT = 1000, NCONT = 2048;
    const long M = (long)Bn * S;

    const int*   ccat      = (const int*)d_in[0];
    const float* ctime     = (const float*)d_in[1];
    const float* cf0       = (const float*)d_in[2];
    const int*   tcat      = (const int*)d_in[3];
    const float* ttime     = (const float*)d_in[4];
    const float* tf0       = (const float*)d_in[5];
    const float* cat_table = (const float*)d_in[6];
    const float* cont_tab  = (const float*)d_in[7];
    const float* pad_emb   = (const float*)d_in[8];
    const float* Wq = (const float*)d_in[9];
    const float* bq = (const float*)d_in[10];
    const float* Wk = (const float*)d_in[11];
    const float* bk = (const float*)d_in[12];
    const float* Wv = (const float*)d_in[13];
    const float* bv = (const float*)d_in[14];
    const float* Wo = (const float*)d_in[15];
    const float* bo = (const float*)d_in[16];
    const float* ln1g = (const float*)d_in[17];
    const float* ln1b = (const float*)d_in[18];
    const float* ln2g = (const float*)d_in[19];
    const float* ln2b = (const float*)d_in[20];
    const float* W1 = (const float*)d_in[21];
    const float* b1 = (const float*)d_in[22];
    const float* W2 = (const float*)d_in[23];
    const float* b2 = (const float*)d_in[24];

    char* wsb = (char*)d_ws;
    size_t off = 0;
    auto alloc = [&](size_t bytes) -> void* {
        off = (off + 255) & ~(size_t)255;
        void* p = wsb + off; off += bytes; return p;
    };

    float*     xf      = (float*)alloc(M * D * 4);
    _Float16*  xb      = (_Float16*)alloc(M * D * 2);
    _Float16*  qkv     = (_Float16*)alloc(M * 3 * D * 2);   // [M][1536] q|k|v
    _Float16*  vT      = (_Float16*)alloc(M * D * 2);
    _Float16*  ob      = (_Float16*)alloc(M * D * 2);
    float*     biasKey = (float*)alloc(M * 4);
    _Float16*  WqkvT = (_Float16*)alloc((size_t)L * 3 * D * D * 2);
    float*     bqkv  = (float*)alloc((size_t)L * 3 * D * 4);
    _Float16*  WoT  = (_Float16*)alloc((size_t)L * D * D * 2);
    _Float16*  W1T  = (_Float16*)alloc((size_t)L * D * DFF * 2);
    _Float16*  W2T  = (_Float16*)alloc((size_t)L * DFF * D * 2);
    _Float16*  catT = (_Float16*)alloc((size_t)1024 * 256 * 2);   // padded to 1024 rows
    _Float16*  conT = (_Float16*)alloc((size_t)NCONT * 128 * 2);

    size_t need_ffh = (size_t)M * DFF * 2;
    _Float16* ffh;
    size_t offAl = (off + 255) & ~(size_t)255;
    if (offAl + need_ffh <= ws_size) ffh = (_Float16*)alloc(need_ffh);
    else ffh = (_Float16*)d_out;

    auto gemm = [&](const _Float16* A, long lda, long sA1, long sA2,
                    const _Float16* Bm, long ldb, long sB1, long sB2,
                    float* Cf, _Float16* Cb, long ldc, long sC1, long sC2,
                    const float* bias, long sb1, long sb2,
                    const float* resid, int Mm, int Nn, int Kk,
                    int Z1, int Z2, float alpha, int relu) {
        dim3 gdim((Nn + 127) / 128, (Mm + 127) / 128, Z1 * Z2);
        gemm_nt<<<gdim, 256, 0, stream>>>(A, lda, sA1, sA2, Bm, ldb, sB1, sB2,
                                          Cf, Cb, ldc, sC1, sC2, bias, sb1, sb2,
                                          resid, Mm, Nn, Kk, Z2, alpha, relu);
    };

    dim3 tb(32, 8);
    // QKV weights concat -> [L][1536][512] NT form
    tcast_k<<<dim3(D / 32, D / 32, L), tb, 0, stream>>>(Wq, WqkvT, D, D, (long)3 * D * D, 0);
    tcast_k<<<dim3(D / 32, D / 32, L), tb, 0, stream>>>(Wk, WqkvT, D, D, (long)3 * D * D, D);
    tcast_k<<<dim3(D / 32, D / 32, L), tb, 0, stream>>>(Wv, WqkvT, D, D, (long)3 * D * D, 2 * D);
    bcat_k<<<dim3((L * 1536 + 255) / 256), 256, 0, stream>>>(bq, bk, bv, bqkv, L);
    tcast_k<<<dim3(D / 32, D / 32, L), tb, 0, stream>>>(Wo, WoT, D, D, (long)D * D, 0);
    tcast_k<<<dim3(DFF / 32, D / 32, L), tb, 0, stream>>>(W1, W1T, D, DFF, (long)D * DFF, 0);
    tcast_k<<<dim3(D / 32, DFF / 32, L), tb, 0, stream>>>(W2, W2T, DFF, D, (long)DFF * D, 0);
    cast_f32_f16_k<<<dim3(512), 256, 0, stream>>>(cat_table, catT, (long)NCAT * 256, (long)1024 * 256);
    cast_f32_f16_k<<<dim3(512), 256, 0, stream>>>(cont_tab, conT, (long)NCONT * 128, (long)NCONT * 128);

    embed_k<<<dim3((unsigned)M), 128, 0, stream>>>(ccat, ctime, cf0, tcat, ttime, tf0,
                                                   cat_table, pad_emb, xf, xb, biasKey);

    for (int l = 0; l < L; l++) {
        // fused QKV projection: [M][1536]
        gemm(xb, D, 0, 0, WqkvT + (size_t)l * 3 * D * D, D, 0, 0, nullptr, qkv, 3 * D, 0, 0,
             bqkv + (size_t)l * 3 * D, 0, 0, nullptr, (int)M, 3 * D, D, 1, 1, 1.f, 0);
        vtrans_k<<<dim3(32, 2, Bn * H), tb, 0, stream>>>(qkv, vT);

        flash_k<<<dim3(Bn * H, S / 64), 256, 0, stream>>>(qkv, vT, biasKey, ob);

        gemm(ob, D, 0, 0, WoT + (size_t)l * D * D, D, 0, 0, xf, nullptr, D, 0, 0,
             bo + l * D, 0, 0, xf, (int)M, D, D, 1, 1, 1.f, 0);
        layernorm_k<<<dim3((unsigned)M), 256, 0, stream>>>(xf, xb, ln1g + l * D, ln1b + l * D);

        gemm(xb, D, 0, 0, W1T + (size_t)l * D * DFF, D, 0, 0, nullptr, ffh, DFF, 0, 0,
             b1 + l * DFF, 0, 0, nullptr, (int)M, DFF, D, 1, 1, 1.f, 1);
        gemm(ffh, DFF, 0, 0, W2T + (size_t)l * DFF * D, DFF, 0, 0, xf, nullptr, D, 0, 0,
             b2 + l * D, 0, 0, xf, (int)M, D, DFF, 1, 1, 1.f, 0);
        layernorm_k<<<dim3((unsigned)M), 256, 0, stream>>>(xf, xb, ln2g + l * D, ln2b + l * D);
    }

    float* out_cat  = (float*)d_out;
    float* out_time = out_cat + (size_t)Bn * 512 * NCAT;
    float* out_f0   = out_time + (size_t)Bn * 512 * NCONT;
    gemm(xb + (size_t)512 * D, D, (long)S * D, 0,
         catT, 256, 0, 0,
         out_cat, nullptr, NCAT, (long)512 * NCAT, 0,
         nullptr, 0, 0, nullptr, 512, NCAT, 256, Bn, 1, 1.f, 0);
    gemm(xb + (size_t)512 * D + 256, D, (long)S * D, 0,
         conT, 128, 0, 0,
         out_time, nullptr, NCONT, (long)512 * NCONT, 0,
         nullptr, 0, 0, nullptr, 512, NCONT, 128, Bn, 1, 1.f, 0);
    gemm(xb + (size_t)512 * D + 384, D, (long)S * D, 0,
         conT, 128, 0, 0,
         out_f0, nullptr, NCONT, (long)512 * NCONT, 0,
         nullptr, 0, 0, nullptr, 512, NCONT, 128, Bn, 1, 1.f, 0);
}